// Round 11
// baseline (1850.350 us; speedup 1.0000x reference)
//
#include <hip/hip_runtime.h>
#include <hip/hip_bf16.h>
#include <hip/hip_fp16.h>

#define NFEAT 128
#define NHID  256
#define NCLASS 40
#define THRESH 0.1f
#define FEPS   1e-8f
#define GUARD2 4e-3f
#define NSTRIPE 384   // gemm1h node-tile stripes; 2*NSTRIPE blocks = 3 blocks/CU

typedef _Float16 v2h __attribute__((ext_vector_type(2)));
typedef _Float16 v8h __attribute__((ext_vector_type(8)));
typedef float f32x4 __attribute__((ext_vector_type(4)));

// fdot2: s += dot(2xfp16, 2xfp16) in one VALU op where available
__device__ __forceinline__ float dot2acc(unsigned int a, unsigned int b, float s) {
#if __has_builtin(__builtin_amdgcn_fdot2)
    return __builtin_amdgcn_fdot2(__builtin_bit_cast(v2h, a),
                                  __builtin_bit_cast(v2h, b), s, false);
#else
    float2 fa = __half22float2(__builtin_bit_cast(__half2, a));
    float2 fb = __half22float2(__builtin_bit_cast(__half2, b));
    return s + fa.x * fb.x + fa.y * fb.y;
#endif
}

// sdot4: acc += dot(4x int8, 4x int8) — v_dot4_i32_i8
__device__ __forceinline__ int dot4acc(int a, int b, int acc) {
#if __has_builtin(__builtin_amdgcn_sdot4)
    return __builtin_amdgcn_sdot4(a, b, acc, false);
#else
#pragma unroll
    for (int k = 0; k < 4; ++k) {
        int av = (a << (24 - 8 * k)) >> 24;
        int bv = (b << (24 - 8 * k)) >> 24;
        acc += av * bv;
    }
    return acc;
#endif
}

__device__ __forceinline__ float waveSum(float v) {
#pragma unroll
    for (int off = 32; off > 0; off >>= 1) v += __shfl_xor(v, off, 64);
    return v;
}

__device__ __forceinline__ float waveMax(float v) {
#pragma unroll
    for (int off = 32; off > 0; off >>= 1) v = fmaxf(v, __shfl_xor(v, off, 64));
    return v;
}

// ---- prep + W-fragment build fused; zero accumulators + nlive ----
__global__ void k_prepw(const float* __restrict__ x,
                        signed char* __restrict__ xq, signed char* __restrict__ xql,
                        float4* __restrict__ meta,
                        float* __restrict__ nrm, float* __restrict__ deg,
                        float* __restrict__ deg2, float* __restrict__ nrmsq,
                        int* __restrict__ nlive,
                        const float* __restrict__ W1f, v8h* __restrict__ w1x,
                        const float* __restrict__ W2f, v8h* __restrict__ w2x,
                        int N, int prepBlocks) {
    int b = blockIdx.x;
    int tid = threadIdx.x;
    if (b == 0 && tid == 0) *nlive = 0;
    if (b < prepBlocks) {
        int r = (b * 256 + tid) >> 6;
        int lane = tid & 63;
        if (r >= N) return;
        float2 a = ((const float2*)(x + (size_t)r * NFEAT))[lane];
        float s = waveSum(a.x * a.x + a.y * a.y);
        float nr = fmaxf(sqrtf(s), FEPS);
        float inv = 1.0f / nr;
        float xn0 = a.x * inv, xn1 = a.y * inv;
        float m = waveMax(fmaxf(fabsf(xn0), fabsf(xn1)));
        float t = (m > 0.f) ? 127.f / m : 0.f;
        float sc = m * (1.0f / 127.f);
        int q0 = __float2int_rn(xn0 * t), q1 = __float2int_rn(xn1 * t);
        q0 = max(-127, min(127, q0));
        q1 = max(-127, min(127, q1));
        char2 pk; pk.x = (signed char)q0; pk.y = (signed char)q1;
        ((char2*)(xq + (size_t)r * NFEAT))[lane] = pk;
        float rq = (m > 0.f) ? 256.0f / sc : 0.f;
        int l0 = __float2int_rn((xn0 - sc * (float)q0) * rq);
        int l1 = __float2int_rn((xn1 - sc * (float)q1) * rq);
        l0 = max(-128, min(127, l0));
        l1 = max(-128, min(127, l1));
        char2 pl; pl.x = (signed char)l0; pl.y = (signed char)l1;
        ((char2*)(xql + (size_t)r * NFEAT))[lane] = pl;
        float asum = waveSum((float)(abs(q0) + abs(q1)));
        float axn  = waveSum(fabsf(xn0) + fabsf(xn1));
        if (lane == 0) {
            meta[r] = make_float4(sc, 0.5f * asum + 33.0f, axn, 0.0f);
            nrm[r] = nr;
            deg[r] = 0.0f;
            deg2[r] = 0.0f;
            nrmsq[r] = 0.0f;
        }
    } else if (b < prepBlocks + 16) {
        int id = (b - prepBlocks) * 256 + tid;     // 0..4095
        int frag = id >> 6, lane = id & 63;
        int kb = frag >> 4, ct = frag & 15;
        int kbase = kb * 32 + (lane >> 4) * 8;
        int n = ct * 16 + (lane & 15);
        v8h v;
#pragma unroll
        for (int j = 0; j < 8; ++j)
            v[j] = (_Float16)W1f[(size_t)(kbase + j) * NHID + n];
        w1x[id] = v;
    } else {
        int id = (b - prepBlocks - 16) * 256 + tid;   // 0..3071
        int part = (id >= 1536) ? 1 : 0;
        int fid = id - part * 1536;
        int frag = fid >> 6, lane = fid & 63;
        int kb = frag / 3, ct = frag % 3;
        int kbase = kb * 32 + (lane >> 4) * 8;
        int n = ct * 16 + (lane & 15);
        v8h v;
#pragma unroll
        for (int j = 0; j < 8; ++j) {
            float wv = (n < NCLASS) ? W2f[(size_t)(kbase + j) * NCLASS + n] : 0.0f;
            _Float16 hi = (_Float16)wv;
            v[j] = part ? (_Float16)(wv - (float)hi) : hi;
        }
        w2x[id] = v;
    }
}

// ---- att1 v5: 16 edges/wave; int8 screen + int8-residual confirm + f32 fallback.
//      Live edges: w1buf[e]=w, deg[r]+=w, ticket-push e into elist (no CSR). ----
__global__ void k_att1(const float* __restrict__ xf,
                       const signed char* __restrict__ xq,
                       const signed char* __restrict__ xql,
                       const float4* __restrict__ meta,
                       const int* __restrict__ row, const int* __restrict__ col,
                       const float* __restrict__ nrm,
                       float* __restrict__ w1, float* __restrict__ deg,
                       int* __restrict__ elist, int* __restrict__ nlive, int E) {
    int wid = (blockIdx.x * blockDim.x + threadIdx.x) >> 6;
    int lane = threadIdx.x & 63;
    int l4 = lane & 3;
    int e = wid * 16 + (lane >> 2);
    if (e >= E) return;
    int r = row[e], c = col[e];
    const int4* qra = (const int4*)(xq + (size_t)r * NFEAT);
    const int4* qca = (const int4*)(xq + (size_t)c * NFEAT);
    int4 qa0 = qra[l4 * 2], qa1 = qra[l4 * 2 + 1];
    int4 qb0 = qca[l4 * 2], qb1 = qca[l4 * 2 + 1];
    int d = 0;
    d = dot4acc(qa0.x, qb0.x, d); d = dot4acc(qa0.y, qb0.y, d);
    d = dot4acc(qa0.z, qb0.z, d); d = dot4acc(qa0.w, qb0.w, d);
    d = dot4acc(qa1.x, qb1.x, d); d = dot4acc(qa1.y, qb1.y, d);
    d = dot4acc(qa1.z, qb1.z, d); d = dot4acc(qa1.w, qb1.w, d);
    d += __shfl_xor(d, 1, 64);
    d += __shfl_xor(d, 2, 64);
    float4 mr = meta[r], mc = meta[c];
    float ub = mr.x * mc.x * ((float)d + mr.y + mc.y);   // >= dot(xn), worst-case
    float sims = 0.0f;
    bool alive = (ub >= THRESH - 1e-5f);
    if (alive) {
        const int4* lra = (const int4*)(xql + (size_t)r * NFEAT);
        const int4* lca = (const int4*)(xql + (size_t)c * NFEAT);
        int4 la0 = lra[l4 * 2], la1 = lra[l4 * 2 + 1];
        int4 lb0 = lca[l4 * 2], lb1 = lca[l4 * 2 + 1];
        int dll = 0, dx = 0;
        dll = dot4acc(la0.x, lb0.x, dll); dll = dot4acc(la0.y, lb0.y, dll);
        dll = dot4acc(la0.z, lb0.z, dll); dll = dot4acc(la0.w, lb0.w, dll);
        dll = dot4acc(la1.x, lb1.x, dll); dll = dot4acc(la1.y, lb1.y, dll);
        dll = dot4acc(la1.z, lb1.z, dll); dll = dot4acc(la1.w, lb1.w, dll);
        dx = dot4acc(qa0.x, lb0.x, dx); dx = dot4acc(qa0.y, lb0.y, dx);
        dx = dot4acc(qa0.z, lb0.z, dx); dx = dot4acc(qa0.w, lb0.w, dx);
        dx = dot4acc(qa1.x, lb1.x, dx); dx = dot4acc(qa1.y, lb1.y, dx);
        dx = dot4acc(qa1.z, lb1.z, dx); dx = dot4acc(qa1.w, lb1.w, dx);
        dx = dot4acc(la0.x, qb0.x, dx); dx = dot4acc(la0.y, qb0.y, dx);
        dx = dot4acc(la0.z, qb0.z, dx); dx = dot4acc(la0.w, qb0.w, dx);
        dx = dot4acc(la1.x, qb1.x, dx); dx = dot4acc(la1.y, qb1.y, dx);
        dx = dot4acc(la1.z, qb1.z, dx); dx = dot4acc(la1.w, qb1.w, dx);
        int conf = dx * 256 + dll;
        conf += __shfl_xor(conf, 1, 64);
        conf += __shfl_xor(conf, 2, 64);
        float ss = mr.x * mc.x;
        sims = ss * ((float)d + (float)conf * (1.0f / 65536.f));
        float errB = (mr.x * mc.z + mc.x * mr.z) * (1.0f / 256.f) + ss * 0.01f + 2e-5f;
        if (__builtin_expect(fabsf(sims - THRESH) < errB, 0)) {
            const float4* fr = (const float4*)(xf + (size_t)r * NFEAT);
            const float4* fc = (const float4*)(xf + (size_t)c * NFEAT);
            float s2 = 0.f;
#pragma unroll
            for (int j = 0; j < 8; ++j) {
                float4 av = fr[l4 + 4 * j], bv = fc[l4 + 4 * j];
                s2 += av.x * bv.x + av.y * bv.y + av.z * bv.z + av.w * bv.w;
            }
            s2 += __shfl_xor(s2, 1, 64);
            s2 += __shfl_xor(s2, 2, 64);
            sims = s2 / (nrm[r] * nrm[c]);
        }
    }
    if (l4 == 0) {
        float w = (alive && sims >= THRESH && r != c) ? sims : 0.0f;
        if (w != 0.0f) {
            w1[e] = w;
            unsafeAtomicAdd(&deg[r], w);
            int pos = atomicAdd(nlive, 1);
            elist[pos] = e;
        }
    }
}

// ---- g1self: xagg[r] = dinv^2 * x[r] (8-lane groups, 8 nodes/wave) ----
__global__ void k_g1self(const float* __restrict__ xf, const float* __restrict__ deg,
                         float* __restrict__ xagg, int N) {
    int tid = blockIdx.x * blockDim.x + threadIdx.x;
    int r = tid >> 3;
    int l = tid & 7;
    if (r >= N) return;
    float d = 1.0f / sqrtf(1.0f + deg[r]);
    float dd = d * d;
    const float4* xr = (const float4*)(xf + (size_t)r * NFEAT) + l * 4;
    float4* xo = (float4*)(xagg + (size_t)r * NFEAT) + l * 4;
#pragma unroll
    for (int j = 0; j < 4; ++j) {
        float4 a = xr[j];
        xo[j] = make_float4(dd * a.x, dd * a.y, dd * a.z, dd * a.w);
    }
}

// ---- g1edge: edge-parallel xagg[r] += nm*x[c] via f32 atomics (8-lane groups).
//      Reassociation-only difference vs serial CSR gather (~1e-7 rel). ----
__global__ __launch_bounds__(256) void k_g1edge(
        const float* __restrict__ xf, const int* __restrict__ row,
        const int* __restrict__ col, const float* __restrict__ w1,
        const float* __restrict__ deg, const int* __restrict__ elist,
        const int* __restrict__ nlive, float* __restrict__ xagg) {
    int tid = blockIdx.x * blockDim.x + threadIdx.x;
    int gid = tid >> 3;
    int l = tid & 7;
    int step = (gridDim.x * blockDim.x) >> 3;
    int total = *nlive;
    for (int i = gid; i < total; i += step) {
        int e = elist[i];
        int r = row[e], c = col[e];
        float w = w1[e];
        float nm = (1.0f / sqrtf(1.0f + deg[r])) * w * (1.0f / sqrtf(1.0f + deg[c]));
        const float4* xc = (const float4*)(xf + (size_t)c * NFEAT) + l * 4;
        float* xr = xagg + (size_t)r * NFEAT + l * 16;
#pragma unroll
        for (int j = 0; j < 4; ++j) {
            float4 b = xc[j];
            unsafeAtomicAdd(&xr[j * 4 + 0], nm * b.x);
            unsafeAtomicAdd(&xr[j * 4 + 1], nm * b.y);
            unsafeAtomicAdd(&xr[j * 4 + 2], nm * b.z);
            unsafeAtomicAdd(&xr[j * 4 + 3], nm * b.w);
        }
    }
}

// ---- gemm1h v8 (MFMA): h = relu(xagg @ W1 + b1); B-frags resident in LDS ----
__global__ __launch_bounds__(256) void k_gemm1h(const float* __restrict__ xagg,
                                                const v8h* __restrict__ w1x,
                                                const float* __restrict__ b1f,
                                                __half* __restrict__ hh16,
                                                float* __restrict__ nrmsq, int N) {
    __shared__ __half2 xsh[64][68];   // A tile: 64 nodes x 64 half2 (+4 pad) = 17.4 KB
    __shared__ v8h bsh[4][8][64];     // B frags for this col-half: 32 KB
    int tid = threadIdx.x;
    int ch = blockIdx.x & 1;          // column half: cols [ch*128, ch*128+128)
    int stripe = blockIdx.x >> 1;

#pragma unroll
    for (int it = 0; it < 8; ++it) {
        int id = it * 256 + tid;               // 0..2047
        int lane = id & 63, fr = id >> 6;      // fr 0..31
        int kb = fr >> 3, ctl = fr & 7;
        bsh[kb][ctl][lane] = w1x[(size_t)(kb * 16 + ch * 8 + ctl) * 64 + lane];
    }

    int w = tid >> 6, lane = tid & 63;
    int c = lane & 15, q = lane >> 4;
    int nb = w * 16;                  // wave's node base within tile

    int T = (N + 63) >> 6;
    for (int t = stripe; t < T; t += NSTRIPE) {
        int i0 = t * 64;
        __syncthreads();              // xsh free of previous tile's readers (+bsh ready)

#pragma unroll
        for (int it = 0; it < 16; ++it) {
            int idx = it * 256 + tid;          // 4096 half2
            int n = idx >> 6, kq = idx & 63;
            int i = i0 + n;
            float2 v = make_float2(0.f, 0.f);
            if (i < N) v = ((const float2*)(xagg + (size_t)i * NFEAT))[kq];
            xsh[n][kq] = __floats2half2_rn(v.x, v.y);
        }
        __syncthreads();

        f32x4 acc[8];
#pragma unroll
        for (int ct = 0; ct < 8; ++ct) acc[ct] = (f32x4){0.f, 0.f, 0.f, 0.f};

#pragma unroll
        for (int kb = 0; kb < 4; ++kb) {
            v8h a = *((const v8h*)&xsh[nb + c][kb * 16 + q * 4]);
#pragma unroll
            for (int ctl = 0; ctl < 8; ++ctl) {
                acc[ctl] = __builtin_amdgcn_mfma_f32_16x16x32_f16(
                    a, bsh[kb][ctl][lane], acc[ctl], 0, 0, 0);
            }
        }

        float s2[4] = {0.f, 0.f, 0.f, 0.f};
        bool full = (i0 + 64 <= N);
#pragma unroll
        for (int ctl = 0; ctl < 8; ++ctl) {
            int n = (ch * 8 + ctl) * 16 + c;
            float bias = b1f[n];
            f32x4 d = acc[ctl];
#pragma unroll
            for (int reg = 0; reg < 4; ++reg) {
                int node = i0 + nb + q * 4 + reg;   // D row = q*4+reg
                float v = fmaxf(d[reg] + bias, 0.f);
                s2[reg] += v * v;
                if (full || node < N) hh16[(size_t)node * NHID + n] = __float2half(v);
            }
        }
#pragma unroll
        for (int off = 1; off < 16; off <<= 1) {
#pragma unroll
            for (int reg = 0; reg < 4; ++reg) s2[reg] += __shfl_xor(s2[reg], off, 64);
        }
        if (c == 0) {
            int base = i0 + nb + q * 4;
#pragma unroll
            for (int reg = 0; reg < 4; ++reg)
                if (base + reg < N) unsafeAtomicAdd(&nrmsq[base + reg], s2[reg]);
        }
    }
}

// ---- att2 edge body (shared by fused + standalone): 8 edges/wave over elist ----
__device__ __forceinline__ void att2_body(
        const float* __restrict__ xagg, const float* __restrict__ W1f,
        const float* __restrict__ b1f, const __half2* __restrict__ hh,
        const int* __restrict__ row, const int* __restrict__ col,
        const float* __restrict__ w1, const int* __restrict__ elist,
        const int* __restrict__ nlive, const float* __restrict__ nrmsq,
        float* __restrict__ w2buf, float* __restrict__ deg2,
        int wid0, int step8, int tid) {
    int lane = tid & 63;
    int l8 = lane & 7, gr8 = lane >> 3;
    int total = *nlive;
    for (int base = wid0 * 8; base < total; base += step8) {
        int pos = base + gr8;
        bool active = (pos < total);
        int e = 0, r = 0, c = 0;
        float sims = 0.f, inv = 0.f;
        if (active) {
            e = elist[pos];
            r = row[e];
            c = col[e];
            const uint4* hr4 = (const uint4*)(hh + (size_t)r * (NHID / 2));
            const uint4* hc4 = (const uint4*)(hh + (size_t)c * (NHID / 2));
            float s = 0.f;
#pragma unroll
            for (int j = 0; j < 4; ++j) {
                uint4 a = hr4[l8 + 8 * j];
                uint4 b = hc4[l8 + 8 * j];
                s = dot2acc(a.x, b.x, s); s = dot2acc(a.y, b.y, s);
                s = dot2acc(a.z, b.z, s); s = dot2acc(a.w, b.w, s);
            }
            s += __shfl_xor(s, 1, 64);
            s += __shfl_xor(s, 2, 64);
            s += __shfl_xor(s, 4, 64);
            float nr = fmaxf(sqrtf(nrmsq[r]), FEPS);
            float nc = fmaxf(sqrtf(nrmsq[c]), FEPS);
            inv = 1.0f / (nr * nc);
            sims = s * inv;
        }
        unsigned long long gm =
            __ballot(active && l8 == 0 && fabsf(sims - THRESH) < GUARD2);
        while (gm) {
            int src = __ffsll(gm) - 1;
            gm &= gm - 1;
            int rr = __shfl(r, src, 64);
            int cc = __shfl(c, src, 64);
            float invv = __shfl(inv, src, 64);
            int j0 = lane * 4;                  // 64 lanes x 4 cols = 256
            float aR[4], aC[4];
#pragma unroll
            for (int q = 0; q < 4; ++q) { aR[q] = b1f[j0 + q]; aC[q] = b1f[j0 + q]; }
            const float* xr = xagg + (size_t)rr * NFEAT;
            const float* xc = xagg + (size_t)cc * NFEAT;
            for (int kk = 0; kk < NFEAT; ++kk) {
                float vr = xr[kk], vc = xc[kk];   // wave-broadcast loads
                float4 wv = *((const float4*)(W1f + (size_t)kk * NHID + j0));
                aR[0] += vr * wv.x; aC[0] += vc * wv.x;
                aR[1] += vr * wv.y; aC[1] += vc * wv.y;
                aR[2] += vr * wv.z; aC[2] += vc * wv.z;
                aR[3] += vr * wv.w; aC[3] += vc * wv.w;
            }
            float dp = 0.f;
#pragma unroll
            for (int q = 0; q < 4; ++q)
                dp += fmaxf(aR[q], 0.f) * fmaxf(aC[q], 0.f);
            float se = waveSum(dp) * invv;
            if (lane == src) sims = se;
        }
        if (active && l8 == 0) {
            float w2 = (sims >= THRESH) ? sims : 0.f;
            w2buf[e] = w2;
            if (w2 != 0.f) unsafeAtomicAdd(&deg2[r], w2);
        }
    }
}

// ---- l2fused: gemm2m role (blocks [0,gemmBlocks)) + att2 role (rest) ----
__global__ __launch_bounds__(256) void k_l2fused(
        const __half2* __restrict__ hh, const v8h* __restrict__ w2x,
        float* __restrict__ g,
        const float* __restrict__ xagg, const float* __restrict__ W1f,
        const float* __restrict__ b1f, const int* __restrict__ row,
        const int* __restrict__ col, const float* __restrict__ w1,
        const int* __restrict__ elist, const int* __restrict__ nlive,
        const float* __restrict__ nrmsq, float* __restrict__ w2buf,
        float* __restrict__ deg2, int gemmBlocks, int N) {
    __shared__ __half2 hs[64][NHID / 2 + 4];   // 33 KB (gemm role only)
    int tid = threadIdx.x;
    if ((int)blockIdx.x < gemmBlocks) {
        int i0 = blockIdx.x * 64;
#pragma unroll
        for (int it = 0; it < 8; ++it) {
            int idx = it * 256 + tid;
            int n = idx >> 5, kq = idx & 31;
            int i = i0 + n;
            uint4 v = make_uint4(0u, 0u, 0u, 0u);
            if (i < N) v = ((const uint4*)(hh + (size_t)i * (NHID / 2)))[kq];
            *((uint4*)&hs[n][kq * 4]) = v;
        }
        __syncthreads();

        int w = tid >> 6, lane = tid & 63;
        int c = lane & 15, q = lane >> 4;
        int nb = w * 16;

        f32x4 acc[3];
#pragma unroll
        for (int t = 0; t < 3; ++t) acc[t] = (f32x4){0.f, 0.f, 0.f, 0.f};

#pragma unroll
        for (int kb = 0; kb < 8; ++kb) {
            v8h a = *((const v8h*)&hs[nb + c][kb * 16 + q * 4]);
            const v8h* bh = w2x + (size_t)(kb * 3) * 64 + lane;
            const v8h* bl = bh + 1536;
#pragma unroll
            for (int ct = 0; ct < 3; ++ct) {
                acc[ct] = __builtin_amdgcn_mfma_f32_16x16x32_f16(a, bh[ct * 64], acc[ct], 0, 0, 0);
                acc[ct] = __builtin_amdgcn_mfma_f32_16x16x32_f16(a, bl[ct * 64], acc[ct], 0, 0, 0);
            }
        }

        bool full = (i0 + 64 <= N);
#pragma unroll
        for (int ct = 0; ct < 3; ++ct) {
            int cls = ct * 16 + c;
            if (cls < NCLASS) {
                f32x4 d = acc[ct];
#pragma unroll
                for (int reg = 0; reg < 4; ++reg) {
                    int node = i0 + nb + q * 4 + reg;
                    if (full || node < N) g[(size_t)node * NCLASS + cls] = d[reg];
                }
            }
        }
    } else {
        int nb2 = gridDim.x - gemmBlocks;
        int wid0 = (((int)blockIdx.x - gemmBlocks) * 256 + tid) >> 6;
        int step8 = (nb2 * 256) >> 3;
        att2_body(xagg, W1f, b1f, hh, row, col, w1, elist, nlive, nrmsq,
                  w2buf, deg2, wid0, step8, tid);
    }
}

// ---- standalone att2 + gemm2m (fallback if ws too small for dedicated g) ----
__global__ __launch_bounds__(256) void k_att2e(
        const float* __restrict__ xagg, const float* __restrict__ W1f,
        const float* __restrict__ b1f, const __half2* __restrict__ hh,
        const int* __restrict__ row, const int* __restrict__ col,
        const float* __restrict__ w1, const int* __restrict__ elist,
        const int* __restrict__ nlive, const float* __restrict__ nrmsq,
        float* __restrict__ w2buf, float* __restrict__ deg2) {
    int tid = threadIdx.x;
    int wid0 = (blockIdx.x * 256 + tid) >> 6;
    int step8 = (gridDim.x * 256) >> 3;
    att2_body(xagg, W1f, b1f, hh, row, col, w1, elist, nlive, nrmsq,
              w2buf, deg2, wid0, step8, tid);
}

__global__ __launch_bounds__(256) void k_gemm2m(const __half2* __restrict__ hh,
                                                const v8h* __restrict__ w2x,
                                                float* __restrict__ g, int N) {
    __shared__ __half2 hs[64][NHID / 2 + 4];
    int tid = threadIdx.x;
    int i0 = blockIdx.x * 64;
#pragma unroll
    for (int it = 0; it < 8; ++it) {
        int idx = it * 256 + tid;
        int n = idx >> 5, kq = idx & 31;
        int i = i0 + n;
        uint4 v = make_uint4(0u, 0u, 0u, 0u);
        if (i < N) v = ((const uint4*)(hh + (size_t)i * (NHID / 2)))[kq];
        *((uint4*)&hs[n][kq * 4]) = v;
    }
    __syncthreads();
    int w = tid >> 6, lane = tid & 63;
    int c = lane & 15, q = lane >> 4;
    int nb = w * 16;
    f32x4 acc[3];
#pragma unroll
    for (int t = 0; t < 3; ++t) acc[t] = (f32x4){0.f, 0.f, 0.f, 0.f};
#pragma unroll
    for (int kb = 0; kb < 8; ++kb) {
        v8h a = *((const v8h*)&hs[nb + c][kb * 16 + q * 4]);
        const v8h* bh = w2x + (size_t)(kb * 3) * 64 + lane;
        const v8h* bl = bh + 1536;
#pragma unroll
        for (int ct = 0; ct < 3; ++ct) {
            acc[ct] = __builtin_amdgcn_mfma_f32_16x16x32_f16(a, bh[ct * 64], acc[ct], 0, 0, 0);
            acc[ct] = __builtin_amdgcn_mfma_f32_16x16x32_f16(a, bl[ct * 64], acc[ct], 0, 0, 0);
        }
    }
    bool full = (i0 + 64 <= N);
#pragma unroll
    for (int ct = 0; ct < 3; ++ct) {
        int cls = ct * 16 + c;
        if (cls < NCLASS) {
            f32x4 d = acc[ct];
#pragma unroll
            for (int reg = 0; reg < 4; ++reg) {
                int node = i0 + nb + q * 4 + reg;
                if (full || node < N) g[(size_t)node * NCLASS + cls] = d[reg];
            }
        }
    }
}

// ---- outinit: out[r] = dinv2^2*g[r] + b2 (dinv2 inline from deg2) ----
__global__ void k_outinit(const float* __restrict__ g, const float* __restrict__ deg2,
                          const float* __restrict__ b2f, float* __restrict__ out, int N) {
    int tid = blockIdx.x * blockDim.x + threadIdx.x;
    int r = tid >> 3;
    int l = tid & 7;
    if (r >= N) return;
    float dr = 1.0f / sqrtf(1.0f + deg2[r]);
    float drr = dr * dr;
    const float* gr = g + (size_t)r * NCLASS;
    float* po = out + (size_t)r * NCLASS;
#pragma unroll
    for (int q = 0; q < 5; ++q) po[l + 8 * q] = drr * gr[l + 8 * q] + b2f[l + 8 * q];
}

// ---- outedge: edge-parallel out[r] += dr*w2*dc*g[c] via atomics (8-lane groups) ----
__global__ __launch_bounds__(256) void k_outedge(
        const float* __restrict__ g, const int* __restrict__ row,
        const int* __restrict__ col, const float* __restrict__ w2buf,
        const float* __restrict__ deg2, const int* __restrict__ elist,
        const int* __restrict__ nlive, float* __restrict__ out) {
    int tid = blockIdx.x * blockDim.x + threadIdx.x;
    int gid = tid >> 3;
    int l = tid & 7;
    int step = (gridDim.x * blockDim.x) >> 3;
    int total = *nlive;
    for (int i = gid; i < total; i += step) {
        int e = elist[i];
        float w2 = w2buf[e];
        if (w2 == 0.f) continue;
        int r = row[e], c = col[e];
        float dr = 1.0f / sqrtf(1.0f + deg2[r]);
        float dc = 1.0f / sqrtf(1.0f + deg2[c]);
        float f = dr * w2 * dc;
        const float* gc = g + (size_t)c * NCLASS;
        float* po = out + (size_t)r * NCLASS;
#pragma unroll
        for (int q = 0; q < 5; ++q)
            unsafeAtomicAdd(&po[l + 8 * q], f * gc[l + 8 * q]);
    }
}

extern "C" void kernel_launch(void* const* d_in, const int* in_sizes, int n_in,
                              void* d_out, int out_size, void* d_ws, size_t ws_size,
                              hipStream_t stream) {
    const float* x  = (const float*)d_in[0];
    const int* row  = (const int*)d_in[1];
    const int* col  = (const int*)d_in[2];
    const float* W1 = (const float*)d_in[3];
    const float* b1 = (const float*)d_in[4];
    const float* W2 = (const float*)d_in[5];
    const float* b2 = (const float*)d_in[6];
    float* out = (float*)d_out;
    const int N = in_sizes[0] / NFEAT;
    const int E = in_sizes[1];

    // ---- workspace layout (~132 MB peak) ----
    char* ws = (char*)d_ws;
    size_t off = 0;
    auto alloc = [&](size_t bytes) {
        char* p = ws + off;
        off += (bytes + 255) & ~(size_t)255;
        return p;
    };
    float*   xagg   = (float*)alloc((size_t)N * NFEAT * 4);   // live thru att2 guard
    __half2* hh     = (__half2*)alloc((size_t)N * NHID * 2);  // fp16 h mirror
    float*   w1buf  = (float*)alloc((size_t)E * 4);
    float*   w2buf  = (float*)alloc((size_t)E * 4);
    int*     elist  = (int*)alloc((size_t)E * 4);             // live-edge list
    float*   nrm    = (float*)alloc((size_t)N * 4);           // layer-1 norms (att1 guard)
    float*   deg    = (float*)alloc((size_t)N * 4);
    float*   deg2   = (float*)alloc((size_t)N * 4);
    float*   nrmsq  = (float*)alloc((size_t)N * 4);           // h row sum-of-squares
    int*     nlive  = (int*)alloc(256);
    v8h*     w1x    = (v8h*)alloc(4096 * 16);                 // W1 B-fragments (64 KB)
    v8h*     w2x    = (v8h*)alloc(3072 * 16);                 // W2 hi/lo B-fragments (48 KB)
    // int8 screen tables overlay xagg (xagg written only later, by g1self):
    signed char* xq  = (signed char*)xagg;
    float4*  meta    = (float4*)(xq + (size_t)N * 128);
    signed char* xql = xq + (size_t)N * 144;
    // dedicated g so the att2 guard can read xagg while gemm2 writes g:
    size_t gBytes = ((size_t)N * NCLASS * 4 + 255) & ~(size_t)255;
    bool fused = (off + gBytes <= ws_size);
    float* g = fused ? (float*)alloc(gBytes) : xagg;   // fallback: overlay (serial)

    const int e16Blocks = (E + 63) / 64;  // 16 edges/wave, 4 waves/block
    const int nBlocks4 = (N + 3) / 4;
    const int nBlocks8 = (N + 31) / 32;   // 8-lane-group node kernels
    const int gemmB    = (N + 63) / 64;

    // ---- layer 1 ----
    k_prepw<<<nBlocks4 + 28, 256, 0, stream>>>(x, xq, xql, meta, nrm, deg, deg2,
                                               nrmsq, nlive, W1, w1x, W2, w2x,
                                               N, nBlocks4);
    k_att1<<<e16Blocks, 256, 0, stream>>>(x, xq, xql, meta, row, col, nrm, w1buf,
                                          deg, elist, nlive, E);
    k_g1self<<<nBlocks8, 256, 0, stream>>>(x, deg, xagg, N);
    k_g1edge<<<2048, 256, 0, stream>>>(x, row, col, w1buf, deg, elist, nlive, xagg);
    k_gemm1h<<<2 * NSTRIPE, 256, 0, stream>>>(xagg, w1x, b1, (__half*)hh, nrmsq, N);

    // ---- layer 2 ----
    if (fused) {
        k_l2fused<<<gemmB + 4096, 256, 0, stream>>>(hh, w2x, g, xagg, W1, b1, row, col,
                                                    w1buf, elist, nlive, nrmsq, w2buf,
                                                    deg2, gemmB, N);
    } else {
        k_att2e<<<4096, 256, 0, stream>>>(xagg, W1, b1, hh, row, col, w1buf, elist,
                                          nlive, nrmsq, w2buf, deg2);
        k_gemm2m<<<gemmB, 256, 0, stream>>>(hh, w2x, g, N);
    }
    k_outinit<<<nBlocks8, 256, 0, stream>>>(g, deg2, b2, out, N);
    k_outedge<<<2048, 256, 0, stream>>>(g, row, col, w2buf, deg2, elist, nlive, out);
}

// Round 12
// 303.730 us; speedup vs baseline: 6.0921x; 6.0921x over previous
//
#include <hip/hip_runtime.h>
#include <hip/hip_bf16.h>
#include <hip/hip_fp16.h>

#define NFEAT 128
#define NHID  256
#define NCLASS 40
#define THRESH 0.1f
#define FEPS   1e-8f
#define GUARD2 4e-3f
#define NSTRIPE 384   // gemm1h node-tile stripes; 2*NSTRIPE blocks = 3 blocks/CU

typedef _Float16 v2h __attribute__((ext_vector_type(2)));
typedef _Float16 v8h __attribute__((ext_vector_type(8)));
typedef float f32x4 __attribute__((ext_vector_type(4)));

// fdot2: s += dot(2xfp16, 2xfp16) in one VALU op where available
__device__ __forceinline__ float dot2acc(unsigned int a, unsigned int b, float s) {
#if __has_builtin(__builtin_amdgcn_fdot2)
    return __builtin_amdgcn_fdot2(__builtin_bit_cast(v2h, a),
                                  __builtin_bit_cast(v2h, b), s, false);
#else
    float2 fa = __half22float2(__builtin_bit_cast(__half2, a));
    float2 fb = __half22float2(__builtin_bit_cast(__half2, b));
    return s + fa.x * fb.x + fa.y * fb.y;
#endif
}

// sdot4: acc += dot(4x int8, 4x int8) — v_dot4_i32_i8
__device__ __forceinline__ int dot4acc(int a, int b, int acc) {
#if __has_builtin(__builtin_amdgcn_sdot4)
    return __builtin_amdgcn_sdot4(a, b, acc, false);
#else
#pragma unroll
    for (int k = 0; k < 4; ++k) {
        int av = (a << (24 - 8 * k)) >> 24;
        int bv = (b << (24 - 8 * k)) >> 24;
        acc += av * bv;
    }
    return acc;
#endif
}

__device__ __forceinline__ float waveSum(float v) {
#pragma unroll
    for (int off = 32; off > 0; off >>= 1) v += __shfl_xor(v, off, 64);
    return v;
}

__device__ __forceinline__ float waveMax(float v) {
#pragma unroll
    for (int off = 32; off > 0; off >>= 1) v = fmaxf(v, __shfl_xor(v, off, 64));
    return v;
}

// ---- prep + W-fragment build fused: blocks [0,prepBlocks) do per-node prep
//      (int8 qh/ql tables + meta + zero-init); 28 tail blocks build the
//      MFMA B-fragments for W1 (16 blocks) and W2 hi/lo (12 blocks). ----
__global__ void k_prepw(const float* __restrict__ x,
                        signed char* __restrict__ xq, signed char* __restrict__ xql,
                        float4* __restrict__ meta,
                        float* __restrict__ nrm, float* __restrict__ deg,
                        float* __restrict__ deg2,
                        int* __restrict__ counts, float* __restrict__ nrmsq,
                        const float* __restrict__ W1f, v8h* __restrict__ w1x,
                        const float* __restrict__ W2f, v8h* __restrict__ w2x,
                        int N, int prepBlocks) {
    int b = blockIdx.x;
    int tid = threadIdx.x;
    if (b < prepBlocks) {
        int r = (b * 256 + tid) >> 6;
        int lane = tid & 63;
        if (r >= N) return;
        float2 a = ((const float2*)(x + (size_t)r * NFEAT))[lane];
        float s = waveSum(a.x * a.x + a.y * a.y);
        float nr = fmaxf(sqrtf(s), FEPS);
        float inv = 1.0f / nr;
        float xn0 = a.x * inv, xn1 = a.y * inv;
        float m = waveMax(fmaxf(fabsf(xn0), fabsf(xn1)));
        float t = (m > 0.f) ? 127.f / m : 0.f;
        float sc = m * (1.0f / 127.f);                  // the s att1 will use
        int q0 = __float2int_rn(xn0 * t), q1 = __float2int_rn(xn1 * t);
        q0 = max(-127, min(127, q0));
        q1 = max(-127, min(127, q1));
        char2 pk; pk.x = (signed char)q0; pk.y = (signed char)q1;
        ((char2*)(xq + (size_t)r * NFEAT))[lane] = pk;
        // residual: ql = rn((xn - s*qh)*256/s), |xn - s*(qh+ql/256)| <= s/256
        float rq = (m > 0.f) ? 256.0f / sc : 0.f;
        int l0 = __float2int_rn((xn0 - sc * (float)q0) * rq);
        int l1 = __float2int_rn((xn1 - sc * (float)q1) * rq);
        l0 = max(-128, min(127, l0));
        l1 = max(-128, min(127, l1));
        char2 pl; pl.x = (signed char)l0; pl.y = (signed char)l1;
        ((char2*)(xql + (size_t)r * NFEAT))[lane] = pl;
        float asum = waveSum((float)(abs(q0) + abs(q1)));
        float axn  = waveSum(fabsf(xn0) + fabsf(xn1));
        if (lane == 0) {
            // P = 0.5*sum|qh| + 32 (e*f term) + 1 slop for f32 eval of the bound
            meta[r] = make_float4(sc, 0.5f * asum + 33.0f, axn, 0.0f);
            nrm[r] = nr;
            deg[r] = 0.0f;
            deg2[r] = 0.0f;
            counts[r] = 0;
            nrmsq[r] = 0.0f;
        }
    } else if (b < prepBlocks + 16) {
        // W1 B-fragments: w1x[((kb*16+ct)*64+lane)], elem j =
        // W1[kb*32 + (lane>>4)*8 + j][ct*16 + (lane&15)]
        int id = (b - prepBlocks) * 256 + tid;     // 0..4095
        int frag = id >> 6, lane = id & 63;
        int kb = frag >> 4, ct = frag & 15;
        int kbase = kb * 32 + (lane >> 4) * 8;
        int n = ct * 16 + (lane & 15);
        v8h v;
#pragma unroll
        for (int j = 0; j < 8; ++j)
            v[j] = (_Float16)W1f[(size_t)(kbase + j) * NHID + n];
        w1x[id] = v;
    } else {
        // W2 hi/lo B-fragments (f32-exact split), zero-padded cols >= NCLASS
        int id = (b - prepBlocks - 16) * 256 + tid;   // 0..3071
        int part = (id >= 1536) ? 1 : 0;
        int fid = id - part * 1536;
        int frag = fid >> 6, lane = fid & 63;
        int kb = frag / 3, ct = frag % 3;
        int kbase = kb * 32 + (lane >> 4) * 8;
        int n = ct * 16 + (lane & 15);
        v8h v;
#pragma unroll
        for (int j = 0; j < 8; ++j) {
            float wv = (n < NCLASS) ? W2f[(size_t)(kbase + j) * NCLASS + n] : 0.0f;
            _Float16 hi = (_Float16)wv;
            v[j] = part ? (_Float16)(wv - (float)hi) : hi;
        }
        w2x[id] = v;
    }
}

// ---- att1 v4: 16 edges/wave (4-lane groups, 32 B/lane). int8 screen +
//      int8-residual confirm + rare f32 fallback. ----
__global__ void k_att1(const float* __restrict__ xf,
                       const signed char* __restrict__ xq,
                       const signed char* __restrict__ xql,
                       const float4* __restrict__ meta,
                       const int* __restrict__ row, const int* __restrict__ col,
                       const float* __restrict__ nrm,
                       float* __restrict__ w1, float* __restrict__ deg,
                       int* __restrict__ counts, int E) {
    int wid = (blockIdx.x * blockDim.x + threadIdx.x) >> 6;
    int lane = threadIdx.x & 63;
    int l4 = lane & 3;
    int e = wid * 16 + (lane >> 2);
    if (e >= E) return;
    int r = row[e], c = col[e];
    const int4* qra = (const int4*)(xq + (size_t)r * NFEAT);
    const int4* qca = (const int4*)(xq + (size_t)c * NFEAT);
    int4 qa0 = qra[l4 * 2], qa1 = qra[l4 * 2 + 1];
    int4 qb0 = qca[l4 * 2], qb1 = qca[l4 * 2 + 1];
    int d = 0;
    d = dot4acc(qa0.x, qb0.x, d); d = dot4acc(qa0.y, qb0.y, d);
    d = dot4acc(qa0.z, qb0.z, d); d = dot4acc(qa0.w, qb0.w, d);
    d = dot4acc(qa1.x, qb1.x, d); d = dot4acc(qa1.y, qb1.y, d);
    d = dot4acc(qa1.z, qb1.z, d); d = dot4acc(qa1.w, qb1.w, d);
    d += __shfl_xor(d, 1, 64);
    d += __shfl_xor(d, 2, 64);
    float4 mr = meta[r], mc = meta[c];
    float ub = mr.x * mc.x * ((float)d + mr.y + mc.y);   // >= dot(xn), worst-case
    float sims = 0.0f;
    bool alive = (ub >= THRESH - 1e-5f);
    if (alive) {
        const int4* lra = (const int4*)(xql + (size_t)r * NFEAT);
        const int4* lca = (const int4*)(xql + (size_t)c * NFEAT);
        int4 la0 = lra[l4 * 2], la1 = lra[l4 * 2 + 1];
        int4 lb0 = lca[l4 * 2], lb1 = lca[l4 * 2 + 1];
        int dll = 0, dx = 0;
        dll = dot4acc(la0.x, lb0.x, dll); dll = dot4acc(la0.y, lb0.y, dll);
        dll = dot4acc(la0.z, lb0.z, dll); dll = dot4acc(la0.w, lb0.w, dll);
        dll = dot4acc(la1.x, lb1.x, dll); dll = dot4acc(la1.y, lb1.y, dll);
        dll = dot4acc(la1.z, lb1.z, dll); dll = dot4acc(la1.w, lb1.w, dll);
        dx = dot4acc(qa0.x, lb0.x, dx); dx = dot4acc(qa0.y, lb0.y, dx);
        dx = dot4acc(qa0.z, lb0.z, dx); dx = dot4acc(qa0.w, lb0.w, dx);
        dx = dot4acc(qa1.x, lb1.x, dx); dx = dot4acc(qa1.y, lb1.y, dx);
        dx = dot4acc(qa1.z, lb1.z, dx); dx = dot4acc(qa1.w, lb1.w, dx);
        dx = dot4acc(la0.x, qb0.x, dx); dx = dot4acc(la0.y, qb0.y, dx);
        dx = dot4acc(la0.z, qb0.z, dx); dx = dot4acc(la0.w, qb0.w, dx);
        dx = dot4acc(la1.x, qb1.x, dx); dx = dot4acc(la1.y, qb1.y, dx);
        dx = dot4acc(la1.z, qb1.z, dx); dx = dot4acc(la1.w, qb1.w, dx);
        int conf = dx * 256 + dll;                 // per-lane <= ~267M, 4-lane sum < 2^31
        conf += __shfl_xor(conf, 1, 64);
        conf += __shfl_xor(conf, 2, 64);
        float ss = mr.x * mc.x;
        sims = ss * ((float)d + (float)conf * (1.0f / 65536.f));
        float errB = (mr.x * mc.z + mc.x * mr.z) * (1.0f / 256.f) + ss * 0.01f + 2e-5f;
        if (__builtin_expect(fabsf(sims - THRESH) < errB, 0)) {
            const float4* fr = (const float4*)(xf + (size_t)r * NFEAT);
            const float4* fc = (const float4*)(xf + (size_t)c * NFEAT);
            float s2 = 0.f;
#pragma unroll
            for (int j = 0; j < 8; ++j) {
                float4 av = fr[l4 + 4 * j], bv = fc[l4 + 4 * j];
                s2 += av.x * bv.x + av.y * bv.y + av.z * bv.z + av.w * bv.w;
            }
            s2 += __shfl_xor(s2, 1, 64);
            s2 += __shfl_xor(s2, 2, 64);
            sims = s2 / (nrm[r] * nrm[c]);
        }
    }
    if (l4 == 0) {
        float w = (alive && sims >= THRESH && r != c) ? sims : 0.0f;
        w1[e] = w;
        if (w != 0.0f) {
            unsafeAtomicAdd(&deg[r], w);
            atomicAdd(&counts[r], 1);
        }
    }
}

// ---- exclusive scan of counts -> rowptr (3-kernel, N <= 512*256) ----
__global__ __launch_bounds__(256) void k_scan1(const int* __restrict__ counts,
                                               int* __restrict__ rowptr,
                                               int* __restrict__ bsum, int N) {
    __shared__ int tmp[256];
    int t = threadIdx.x, i = blockIdx.x * 256 + t;
    int v = (i < N) ? counts[i] : 0;
    tmp[t] = v;
    __syncthreads();
    for (int off = 1; off < 256; off <<= 1) {
        int add = (t >= off) ? tmp[t - off] : 0;
        __syncthreads();
        tmp[t] += add;
        __syncthreads();
    }
    if (i < N) rowptr[i] = tmp[t] - v;
    if (t == 255) bsum[blockIdx.x] = tmp[t];
}

__global__ __launch_bounds__(512) void k_scan2(int* __restrict__ bsum, int nb) {
    __shared__ int tmp[512];
    int t = threadIdx.x;
    int v = (t < nb) ? bsum[t] : 0;
    tmp[t] = v;
    __syncthreads();
    for (int off = 1; off < 512; off <<= 1) {
        int add = (t >= off) ? tmp[t - off] : 0;
        __syncthreads();
        tmp[t] += add;
        __syncthreads();
    }
    if (t < nb) bsum[t] = tmp[t] - v;
}

__global__ void k_scan3(int* __restrict__ rowptr, const int* __restrict__ bsum, int N) {
    int i = blockIdx.x * 256 + threadIdx.x;
    if (i < N) rowptr[i] += bsum[blockIdx.x];
}

// ---- fill CSR: edata[pos] = (col, norm); esrc[pos] = r ----
__global__ void k_fill(const int* __restrict__ row, const int* __restrict__ col,
                       const float* __restrict__ wbuf, const float* __restrict__ deg,
                       int* __restrict__ rowptr, int2* __restrict__ edata,
                       int* __restrict__ esrc, int E) {
    int e = blockIdx.x * blockDim.x + threadIdx.x;
    if (e >= E) return;
    float w = wbuf[e];
    if (w == 0.0f) return;
    int r = row[e], c = col[e];
    float dr = 1.0f / sqrtf(1.0f + deg[r]);
    float dc = 1.0f / sqrtf(1.0f + deg[c]);
    float nm = dr * w * dc;
    int pos = atomicAdd(&rowptr[r], 1);
    edata[pos] = make_int2(c, __float_as_int(nm));
    esrc[pos] = r;
}

// ---- gather1 v3: 8-lane group per node (8 nodes/wave). Bit-exact order. ----
__global__ void k_gather1(const float* __restrict__ xf, const int* __restrict__ rowptr,
                          const int* __restrict__ counts, const float* __restrict__ deg,
                          const int2* __restrict__ edata, float* __restrict__ xagg, int N) {
    int tid = blockIdx.x * blockDim.x + threadIdx.x;
    int r = tid >> 3;
    int l = tid & 7;
    if (r >= N) return;
    int cnt = counts[r];
    int start = rowptr[r] - cnt;
    float d = 1.0f / sqrtf(1.0f + deg[r]);
    float dd = d * d;
    const float4* xr = (const float4*)(xf + (size_t)r * NFEAT) + l * 4;
    float4 c0, c1, c2, c3;
    {
        float4 a0 = xr[0], a1 = xr[1], a2 = xr[2], a3 = xr[3];
        c0 = make_float4(dd * a0.x, dd * a0.y, dd * a0.z, dd * a0.w);
        c1 = make_float4(dd * a1.x, dd * a1.y, dd * a1.z, dd * a1.w);
        c2 = make_float4(dd * a2.x, dd * a2.y, dd * a2.z, dd * a2.w);
        c3 = make_float4(dd * a3.x, dd * a3.y, dd * a3.z, dd * a3.w);
    }
    for (int k = 0; k < cnt; ++k) {
        int2 ed = edata[start + k];
        float nm = __int_as_float(ed.y);
        const float4* xc = (const float4*)(xf + (size_t)ed.x * NFEAT) + l * 4;
        float4 b0 = xc[0], b1 = xc[1], b2 = xc[2], b3 = xc[3];
        c0.x += nm * b0.x; c0.y += nm * b0.y; c0.z += nm * b0.z; c0.w += nm * b0.w;
        c1.x += nm * b1.x; c1.y += nm * b1.y; c1.z += nm * b1.z; c1.w += nm * b1.w;
        c2.x += nm * b2.x; c2.y += nm * b2.y; c2.z += nm * b2.z; c2.w += nm * b2.w;
        c3.x += nm * b3.x; c3.y += nm * b3.y; c3.z += nm * b3.z; c3.w += nm * b3.w;
    }
    float4* xo = (float4*)(xagg + (size_t)r * NFEAT) + l * 4;
    xo[0] = c0; xo[1] = c1; xo[2] = c2; xo[3] = c3;
}

// ---- gemm1h v8 (MFMA): h = relu(xagg @ W1 + b1); B-frags resident in LDS ----
__global__ __launch_bounds__(256) void k_gemm1h(const float* __restrict__ xagg,
                                                const v8h* __restrict__ w1x,
                                                const float* __restrict__ b1f,
                                                __half* __restrict__ hh16,
                                                float* __restrict__ nrmsq, int N) {
    __shared__ __half2 xsh[64][68];   // A tile: 64 nodes x 64 half2 (+4 pad) = 17.4 KB
    __shared__ v8h bsh[4][8][64];     // B frags for this col-half: 32 KB
    int tid = threadIdx.x;
    int ch = blockIdx.x & 1;          // column half: cols [ch*128, ch*128+128)
    int stripe = blockIdx.x >> 1;

#pragma unroll
    for (int it = 0; it < 8; ++it) {
        int id = it * 256 + tid;               // 0..2047
        int lane = id & 63, fr = id >> 6;      // fr 0..31
        int kb = fr >> 3, ctl = fr & 7;
        bsh[kb][ctl][lane] = w1x[(size_t)(kb * 16 + ch * 8 + ctl) * 64 + lane];
    }

    int w = tid >> 6, lane = tid & 63;
    int c = lane & 15, q = lane >> 4;
    int nb = w * 16;                  // wave's node base within tile

    int T = (N + 63) >> 6;
    for (int t = stripe; t < T; t += NSTRIPE) {
        int i0 = t * 64;
        __syncthreads();              // xsh free of previous tile's readers (+bsh ready)

#pragma unroll
        for (int it = 0; it < 16; ++it) {
            int idx = it * 256 + tid;          // 4096 half2
            int n = idx >> 6, kq = idx & 63;
            int i = i0 + n;
            float2 v = make_float2(0.f, 0.f);
            if (i < N) v = ((const float2*)(xagg + (size_t)i * NFEAT))[kq];
            xsh[n][kq] = __floats2half2_rn(v.x, v.y);
        }
        __syncthreads();

        f32x4 acc[8];
#pragma unroll
        for (int ct = 0; ct < 8; ++ct) acc[ct] = (f32x4){0.f, 0.f, 0.f, 0.f};

#pragma unroll
        for (int kb = 0; kb < 4; ++kb) {
            v8h a = *((const v8h*)&xsh[nb + c][kb * 16 + q * 4]);
#pragma unroll
            for (int ctl = 0; ctl < 8; ++ctl) {
                acc[ctl] = __builtin_amdgcn_mfma_f32_16x16x32_f16(
                    a, bsh[kb][ctl][lane], acc[ctl], 0, 0, 0);
            }
        }

        float s2[4] = {0.f, 0.f, 0.f, 0.f};
        bool full = (i0 + 64 <= N);
#pragma unroll
        for (int ctl = 0; ctl < 8; ++ctl) {
            int n = (ch * 8 + ctl) * 16 + c;
            float bias = b1f[n];
            f32x4 d = acc[ctl];
#pragma unroll
            for (int reg = 0; reg < 4; ++reg) {
                int node = i0 + nb + q * 4 + reg;   // D row = q*4+reg
                float v = fmaxf(d[reg] + bias, 0.f);
                s2[reg] += v * v;
                if (full || node < N) hh16[(size_t)node * NHID + n] = __float2half(v);
            }
        }
#pragma unroll
        for (int off = 1; off < 16; off <<= 1) {
#pragma unroll
            for (int reg = 0; reg < 4; ++reg) s2[reg] += __shfl_xor(s2[reg], off, 64);
        }
        if (c == 0) {
            int base = i0 + nb + q * 4;
#pragma unroll
            for (int reg = 0; reg < 4; ++reg)
                if (base + reg < N) unsafeAtomicAdd(&nrmsq[base + reg], s2[reg]);
        }
    }
}

// ---- l2fused: gemm2m role (blocks [0,gemmBlocks)) + att2e role (rest).
//      Independent work overlapped in one launch; g is a DEDICATED buffer so
//      att2e's rare guard path can still read xagg. ----
__global__ __launch_bounds__(256) void k_l2fused(
        // gemm2m args
        const __half2* __restrict__ hh, const v8h* __restrict__ w2x,
        float* __restrict__ g,
        // att2e args
        const float* __restrict__ xagg, const float* __restrict__ W1f,
        const float* __restrict__ b1f, const int* __restrict__ esrc,
        const int2* __restrict__ edata, const float* __restrict__ nrmsq,
        const int* __restrict__ etot, float* __restrict__ w2csr,
        float* __restrict__ deg2,
        int gemmBlocks, int N) {
    __shared__ __half2 hs[64][NHID / 2 + 4];   // 33 KB (gemm role only)
    int tid = threadIdx.x;
    if ((int)blockIdx.x < gemmBlocks) {
        // ---------------- gemm2m role: g = h @ W2 (MFMA, hi/lo W2) ----------------
        int i0 = blockIdx.x * 64;
#pragma unroll
        for (int it = 0; it < 8; ++it) {
            int idx = it * 256 + tid;
            int n = idx >> 5, kq = idx & 31;     // row n, 16B-chunk kq (32 per row)
            int i = i0 + n;
            uint4 v = make_uint4(0u, 0u, 0u, 0u);
            if (i < N) v = ((const uint4*)(hh + (size_t)i * (NHID / 2)))[kq];
            *((uint4*)&hs[n][kq * 4]) = v;
        }
        __syncthreads();

        int w = tid >> 6, lane = tid & 63;
        int c = lane & 15, q = lane >> 4;
        int nb = w * 16;

        f32x4 acc[3];
#pragma unroll
        for (int t = 0; t < 3; ++t) acc[t] = (f32x4){0.f, 0.f, 0.f, 0.f};

#pragma unroll
        for (int kb = 0; kb < 8; ++kb) {
            v8h a = *((const v8h*)&hs[nb + c][kb * 16 + q * 4]);
            const v8h* bh = w2x + (size_t)(kb * 3) * 64 + lane;   // hi frags
            const v8h* bl = bh + 1536;                            // lo frags
#pragma unroll
            for (int ct = 0; ct < 3; ++ct) {
                acc[ct] = __builtin_amdgcn_mfma_f32_16x16x32_f16(a, bh[ct * 64], acc[ct], 0, 0, 0);
                acc[ct] = __builtin_amdgcn_mfma_f32_16x16x32_f16(a, bl[ct * 64], acc[ct], 0, 0, 0);
            }
        }

        bool full = (i0 + 64 <= N);
#pragma unroll
        for (int ct = 0; ct < 3; ++ct) {
            int cls = ct * 16 + c;
            if (cls < NCLASS) {
                f32x4 d = acc[ct];
#pragma unroll
                for (int reg = 0; reg < 4; ++reg) {
                    int node = i0 + nb + q * 4 + reg;   // D row = q*4+reg
                    if (full || node < N) g[(size_t)node * NCLASS + cls] = d[reg];
                }
            }
        }
    } else {
        // ---------------- att2e role: 8 CSR entries/wave, grid-stride ----------------
        int lane = tid & 63;
        int l8 = lane & 7, gr8 = lane >> 3;
        int nb2 = gridDim.x - gemmBlocks;
        int wid0 = (((int)blockIdx.x - gemmBlocks) * 256 + tid) >> 6;
        int step = (nb2 * 256) >> 3;            // waves-in-role * 8 edges
        int total = *etot;                      // = rowptr[N-1] after fill
        for (int base = wid0 * 8; base < total; base += step) {
            int pos = base + gr8;
            bool active = (pos < total);
            int r = 0, c = 0;
            float sims = 0.f, inv = 0.f;
            if (active) {
                r = esrc[pos];
                c = edata[pos].x;
                const uint4* hr4 = (const uint4*)(hh + (size_t)r * (NHID / 2));
                const uint4* hc4 = (const uint4*)(hh + (size_t)c * (NHID / 2));
                float s = 0.f;
#pragma unroll
                for (int j = 0; j < 4; ++j) {
                    uint4 a = hr4[l8 + 8 * j];
                    uint4 b = hc4[l8 + 8 * j];
                    s = dot2acc(a.x, b.x, s); s = dot2acc(a.y, b.y, s);
                    s = dot2acc(a.z, b.z, s); s = dot2acc(a.w, b.w, s);
                }
                s += __shfl_xor(s, 1, 64);
                s += __shfl_xor(s, 2, 64);
                s += __shfl_xor(s, 4, 64);
                float nr = fmaxf(sqrtf(nrmsq[r]), FEPS);
                float nc = fmaxf(sqrtf(nrmsq[c]), FEPS);
                inv = 1.0f / (nr * nc);
                sims = s * inv;
            }
            unsigned long long gm =
                __ballot(active && l8 == 0 && fabsf(sims - THRESH) < GUARD2);
            while (gm) {
                int src = __ffsll(gm) - 1;
                gm &= gm - 1;
                int rr = __shfl(r, src, 64);
                int cc = __shfl(c, src, 64);
                float invv = __shfl(inv, src, 64);
                int j0 = lane * 4;              // 64 lanes x 4 cols = 256
                float aR[4], aC[4];
#pragma unroll
                for (int q = 0; q < 4; ++q) { aR[q] = b1f[j0 + q]; aC[q] = b1f[j0 + q]; }
                const float* xr = xagg + (size_t)rr * NFEAT;
                const float* xc = xagg + (size_t)cc * NFEAT;
                for (int kk = 0; kk < NFEAT; ++kk) {
                    float vr = xr[kk], vc = xc[kk];   // wave-broadcast loads
                    float4 wv = *((const float4*)(W1f + (size_t)kk * NHID + j0));
                    aR[0] += vr * wv.x; aC[0] += vc * wv.x;
                    aR[1] += vr * wv.y; aC[1] += vc * wv.y;
                    aR[2] += vr * wv.z; aC[2] += vc * wv.z;
                    aR[3] += vr * wv.w; aC[3] += vc * wv.w;
                }
                float dp = 0.f;
#pragma unroll
                for (int q = 0; q < 4; ++q)
                    dp += fmaxf(aR[q], 0.f) * fmaxf(aC[q], 0.f);
                float se = waveSum(dp) * invv;
                if (lane == src) sims = se;
            }
            if (active && l8 == 0) {
                float w2 = (sims >= THRESH) ? sims : 0.f;
                w2csr[pos] = w2;
                if (w2 != 0.f) unsafeAtomicAdd(&deg2[r], w2);
            }
        }
    }
}

// ---- standalone att2e + gemm2m (fallback path if ws too small for separate g) ----
__global__ __launch_bounds__(256) void k_att2e(
        const float* __restrict__ xagg, const float* __restrict__ W1f,
        const float* __restrict__ b1f, const __half2* __restrict__ hh,
        const int* __restrict__ esrc, const int2* __restrict__ edata,
        const float* __restrict__ nrmsq, const int* __restrict__ etot,
        float* __restrict__ w2csr, float* __restrict__ deg2) {
    int lane = threadIdx.x & 63;
    int l8 = lane & 7, g = lane >> 3;
    int wid0 = (blockIdx.x * blockDim.x + threadIdx.x) >> 6;
    int step = (gridDim.x * blockDim.x) >> 3;
    int total = *etot;
    for (int base = wid0 * 8; base < total; base += step) {
        int pos = base + g;
        bool active = (pos < total);
        int r = 0, c = 0;
        float sims = 0.f, inv = 0.f;
        if (active) {
            r = esrc[pos];
            c = edata[pos].x;
            const uint4* hr4 = (const uint4*)(hh + (size_t)r * (NHID / 2));
            const uint4* hc4 = (const uint4*)(hh + (size_t)c * (NHID / 2));
            float s = 0.f;
#pragma unroll
            for (int j = 0; j < 4; ++j) {
                uint4 a = hr4[l8 + 8 * j];
                uint4 b = hc4[l8 + 8 * j];
                s = dot2acc(a.x, b.x, s); s = dot2acc(a.y, b.y, s);
                s = dot2acc(a.z, b.z, s); s = dot2acc(a.w, b.w, s);
            }
            s += __shfl_xor(s, 1, 64);
            s += __shfl_xor(s, 2, 64);
            s += __shfl_xor(s, 4, 64);
            float nr = fmaxf(sqrtf(nrmsq[r]), FEPS);
            float nc = fmaxf(sqrtf(nrmsq[c]), FEPS);
            inv = 1.0f / (nr * nc);
            sims = s * inv;
        }
        unsigned long long gm =
            __ballot(active && l8 == 0 && fabsf(sims - THRESH) < GUARD2);
        while (gm) {
            int src = __ffsll(gm) - 1;
            gm &= gm - 1;
            int rr = __shfl(r, src, 64);
            int cc = __shfl(c, src, 64);
            float invv = __shfl(inv, src, 64);
            int j0 = lane * 4;
            float aR[4], aC[4];
#pragma unroll
            for (int q = 0; q < 4; ++q) { aR[q] = b1f[j0 + q]; aC[q] = b1f[j0 + q]; }
            const float* xr = xagg + (size_t)rr * NFEAT;
            const float* xc = xagg + (size_t)cc * NFEAT;
            for (int kk = 0; kk < NFEAT; ++kk) {
                float vr = xr[kk], vc = xc[kk];
                float4 wv = *((const float4*)(W1f + (size_t)kk * NHID + j0));
                aR[0] += vr * wv.x; aC[0] += vc * wv.x;
                aR[1] += vr * wv.y; aC[1] += vc * wv.y;
                aR[2] += vr * wv.z; aC[2] += vc * wv.z;
                aR[3] += vr * wv.w; aC[3] += vc * wv.w;
            }
            float dp = 0.f;
#pragma unroll
            for (int q = 0; q < 4; ++q)
                dp += fmaxf(aR[q], 0.f) * fmaxf(aC[q], 0.f);
            float se = waveSum(dp) * invv;
            if (lane == src) sims = se;
        }
        if (active && l8 == 0) {
            float w2 = (sims >= THRESH) ? sims : 0.f;
            w2csr[pos] = w2;
            if (w2 != 0.f) unsafeAtomicAdd(&deg2[r], w2);
        }
    }
}

__global__ __launch_bounds__(256) void k_gemm2m(const __half2* __restrict__ hh,
                                                const v8h* __restrict__ w2x,
                                                float* __restrict__ g, int N) {
    __shared__ __half2 hs[64][NHID / 2 + 4];
    int tid = threadIdx.x;
    int i0 = blockIdx.x * 64;
#pragma unroll
    for (int it = 0; it < 8; ++it) {
        int idx = it * 256 + tid;
        int n = idx >> 5, kq = idx & 31;
        int i = i0 + n;
        uint4 v = make_uint4(0u, 0u, 0u, 0u);
        if (i < N) v = ((const uint4*)(hh + (size_t)i * (NHID / 2)))[kq];
        *((uint4*)&hs[n][kq * 4]) = v;
    }
    __syncthreads();
    int w = tid >> 6, lane = tid & 63;
    int c = lane & 15, q = lane >> 4;
    int nb = w * 16;
    f32x4 acc[3];
#pragma unroll
    for (int t = 0; t < 3; ++t) acc[t] = (f32x4){0.f, 0.f, 0.f, 0.f};
#pragma unroll
    for (int kb = 0; kb < 8; ++kb) {
        v8h a = *((const v8h*)&hs[nb + c][kb * 16 + q * 4]);
        const v8h* bh = w2x + (size_t)(kb * 3) * 64 + lane;
        const v8h* bl = bh + 1536;
#pragma unroll
        for (int ct = 0; ct < 3; ++ct) {
            acc[ct] = __builtin_amdgcn_mfma_f32_16x16x32_f16(a, bh[ct * 64], acc[ct], 0, 0, 0);
            acc[ct] = __builtin_amdgcn_mfma_f32_16x16x32_f16(a, bl[ct * 64], acc[ct], 0, 0, 0);
        }
    }
    bool full = (i0 + 64 <= N);
#pragma unroll
    for (int ct = 0; ct < 3; ++ct) {
        int cls = ct * 16 + c;
        if (cls < NCLASS) {
            f32x4 d = acc[ct];
#pragma unroll
            for (int reg = 0; reg < 4; ++reg) {
                int node = i0 + nb + q * 4 + reg;
                if (full || node < N) g[(size_t)node * NCLASS + cls] = d[reg];
            }
        }
    }
}

// ---- gather2 v4: 8-lane group per node; dinv2 computed INLINE from deg2
//      (identical expression as the old k_dinv2 -> bit-identical values). ----
__global__ void k_gather2(const float* __restrict__ g, const int* __restrict__ rowptr,
                          const int* __restrict__ counts, const float* __restrict__ deg2,
                          const float* __restrict__ b2f, const int2* __restrict__ edata,
                          const float* __restrict__ w2csr, float* __restrict__ out, int N) {
    int tid = blockIdx.x * blockDim.x + threadIdx.x;
    int r = tid >> 3;
    int l = tid & 7;
    if (r >= N) return;
    int cnt = counts[r];
    int start = rowptr[r] - cnt;
    float dr = 1.0f / sqrtf(1.0f + deg2[r]);
    float drr = dr * dr;
    const float* gr = g + (size_t)r * NCLASS;
    float acc[5];
#pragma unroll
    for (int q = 0; q < 5; ++q) acc[q] = drr * gr[l + 8 * q] + b2f[l + 8 * q];
    for (int k = 0; k < cnt; ++k) {
        int2 ed = edata[start + k];
        float w2 = w2csr[start + k];
        float dc = 1.0f / sqrtf(1.0f + deg2[ed.x]);
        float f = dr * w2 * dc;
        const float* gc = g + (size_t)ed.x * NCLASS;
#pragma unroll
        for (int q = 0; q < 5; ++q) acc[q] += f * gc[l + 8 * q];
    }
    float* po = out + (size_t)r * NCLASS;
#pragma unroll
    for (int q = 0; q < 5; ++q) po[l + 8 * q] = acc[q];
}

extern "C" void kernel_launch(void* const* d_in, const int* in_sizes, int n_in,
                              void* d_out, int out_size, void* d_ws, size_t ws_size,
                              hipStream_t stream) {
    const float* x  = (const float*)d_in[0];
    const int* row  = (const int*)d_in[1];
    const int* col  = (const int*)d_in[2];
    const float* W1 = (const float*)d_in[3];
    const float* b1 = (const float*)d_in[4];
    const float* W2 = (const float*)d_in[5];
    const float* b2 = (const float*)d_in[6];
    float* out = (float*)d_out;
    const int N = in_sizes[0] / NFEAT;
    const int E = in_sizes[1];

    // ---- workspace layout ----
    char* ws = (char*)d_ws;
    size_t off = 0;
    auto alloc = [&](size_t bytes) {
        char* p = ws + off;
        off += (bytes + 255) & ~(size_t)255;
        return p;
    };
    float*   xagg   = (float*)alloc((size_t)N * NFEAT * 4);   // live thru att2e
    __half2* hh     = (__half2*)alloc((size_t)N * NHID * 2);  // fp16 h mirror
    float*   w1buf  = (float*)alloc((size_t)E * 4);
    float*   w2csr  = (float*)alloc((size_t)E * 4);
    int2*    edata  = (int2*)alloc((size_t)E * 8);
    int*     esrc   = (int*)alloc((size_t)E * 4);             // CSR source nodes
    float*   nrm    = (float*)alloc((size_t)N * 4);           // layer-1 norms (att1 guard)
    float*   deg    = (float*)alloc((size_t)N * 4);           // degsum layer 1
    int*     counts = (int*)alloc((size_t)N * 4);
    int*     rowptr = (int*)alloc((size_t)N * 4);
    int*     bsum   = (int*)alloc(512 * 4);
    v8h*     w1x    = (v8h*)alloc(4096 * 16);                 // W1 B-fragments (64 KB)
    v8h*     w2x    = (v8h*)alloc(3072 * 16);                 // W2 hi/lo B-fragments (48 KB)
    float*   nrmsq  = (float*)alloc((size_t)N * 4);           // h row sum-of-squares
    float*   deg2   = (float*)alloc((size_t)N * 4);           // layer-2 degree sums
    // int8 screen tables overlay xagg (xagg written only later, by k_gather1):
    signed char* xq  = (signed char*)xagg;
    float4*  meta    = (float4*)(xq + (size_t)N * 128);
    signed char* xql = xq + (size_t)N * 144;
    // dedicated g (so att2e's guard can read xagg while gemm2m writes g):
    size_t gBytes = ((size_t)N * NCLASS * 4 + 255) & ~(size_t)255;
    bool fused = (off + gBytes <= ws_size);
    float* g = fused ? (float*)alloc(gBytes) : xagg;   // fallback: overlay (serial)

    const int e16Blocks = (E + 63) / 64;  // 16 edges/wave, 4 waves/block
    const int eBlocks1 = (E + 255) / 256;
    const int nBlocks4 = (N + 3) / 4;
    const int nBlocks8 = (N + 31) / 32;   // 8-lane-group kernels (8 nodes/wave)
    const int scanB    = (N + 255) / 256;
    const int gemmB    = (N + 63) / 64;

    // ---- layer 1 ----
    k_prepw<<<nBlocks4 + 28, 256, 0, stream>>>(x, xq, xql, meta, nrm, deg, deg2,
                                               counts, nrmsq, W1, w1x, W2, w2x,
                                               N, nBlocks4);
    k_att1<<<e16Blocks, 256, 0, stream>>>(x, xq, xql, meta, row, col, nrm, w1buf, deg,
                                          counts, E);
    k_scan1<<<scanB, 256, 0, stream>>>(counts, rowptr, bsum, N);
    k_scan2<<<1, 512, 0, stream>>>(bsum, scanB);
    k_scan3<<<scanB, 256, 0, stream>>>(rowptr, bsum, N);
    k_fill<<<eBlocks1, 256, 0, stream>>>(row, col, w1buf, deg, rowptr, edata, esrc, E);
    k_gather1<<<nBlocks8, 256, 0, stream>>>(x, rowptr, counts, deg, edata, xagg, N);
    k_gemm1h<<<2 * NSTRIPE, 256, 0, stream>>>(xagg, w1x, b1, (__half*)hh, nrmsq, N);

    // ---- layer 2 ----
    if (fused) {
        k_l2fused<<<gemmB + 4096, 256, 0, stream>>>(hh, w2x, g, xagg, W1, b1, esrc,
                                                    edata, nrmsq, rowptr + (N - 1),
                                                    w2csr, deg2, gemmB, N);
    } else {
        k_att2e<<<4096, 256, 0, stream>>>(xagg, W1, b1, hh, esrc, edata, nrmsq,
                                          rowptr + (N - 1), w2csr, deg2);
        k_gemm2m<<<gemmB, 256, 0, stream>>>(hh, w2x, g, N);
    }
    k_gather2<<<nBlocks8, 256, 0, stream>>>(g, rowptr, counts, deg2, b2, edata, w2csr,
                                            out, N);
}

// Round 13
// 302.455 us; speedup vs baseline: 6.1178x; 1.0042x over previous
//
#include <hip/hip_runtime.h>
#include <hip/hip_bf16.h>
#include <hip/hip_fp16.h>

#define NFEAT 128
#define NHID  256
#define NCLASS 40
#define THRESH 0.1f
#define FEPS   1e-8f
#define GUARD2 4e-3f
#define NSTRIPE 384   // gemm1h node-tile stripes; 2*NSTRIPE blocks = 3 blocks/CU

typedef _Float16 v2h __attribute__((ext_vector_type(2)));
typedef _Float16 v8h __attribute__((ext_vector_type(8)));
typedef float f32x4 __attribute__((ext_vector_type(4)));

// fdot2: s += dot(2xfp16, 2xfp16) in one VALU op where available
__device__ __forceinline__ float dot2acc(unsigned int a, unsigned int b, float s) {
#if __has_builtin(__builtin_amdgcn_fdot2)
    return __builtin_amdgcn_fdot2(__builtin_bit_cast(v2h, a),
                                  __builtin_bit_cast(v2h, b), s, false);
#else
    float2 fa = __half22float2(__builtin_bit_cast(__half2, a));
    float2 fb = __half22float2(__builtin_bit_cast(__half2, b));
    return s + fa.x * fb.x + fa.y * fb.y;
#endif
}

// sdot4: acc += dot(4x int8, 4x int8) — v_dot4_i32_i8
__device__ __forceinline__ int dot4acc(int a, int b, int acc) {
#if __has_builtin(__builtin_amdgcn_sdot4)
    return __builtin_amdgcn_sdot4(a, b, acc, false);
#else
#pragma unroll
    for (int k = 0; k < 4; ++k) {
        int av = (a << (24 - 8 * k)) >> 24;
        int bv = (b << (24 - 8 * k)) >> 24;
        acc += av * bv;
    }
    return acc;
#endif
}

__device__ __forceinline__ float waveSum(float v) {
#pragma unroll
    for (int off = 32; off > 0; off >>= 1) v += __shfl_xor(v, off, 64);
    return v;
}

__device__ __forceinline__ float waveMax(float v) {
#pragma unroll
    for (int off = 32; off > 0; off >>= 1) v = fmaxf(v, __shfl_xor(v, off, 64));
    return v;
}

// ---- prep + W-fragment build fused. int8 tables INTERLEAVED per row:
//      xqi[r*256 .. r*256+127] = qh, [r*256+128 .. +255] = ql  (confirm lines
//      adjacent to screen lines -> better L3/DRAM-sector locality). ----
__global__ void k_prepw(const float* __restrict__ x,
                        signed char* __restrict__ xqi,
                        float4* __restrict__ meta,
                        float* __restrict__ nrm, float* __restrict__ deg,
                        float* __restrict__ deg2,
                        int* __restrict__ counts, float* __restrict__ nrmsq,
                        const float* __restrict__ W1f, v8h* __restrict__ w1x,
                        const float* __restrict__ W2f, v8h* __restrict__ w2x,
                        int N, int prepBlocks) {
    int b = blockIdx.x;
    int tid = threadIdx.x;
    if (b < prepBlocks) {
        int r = (b * 256 + tid) >> 6;
        int lane = tid & 63;
        if (r >= N) return;
        float2 a = ((const float2*)(x + (size_t)r * NFEAT))[lane];
        float s = waveSum(a.x * a.x + a.y * a.y);
        float nr = fmaxf(sqrtf(s), FEPS);
        float inv = 1.0f / nr;
        float xn0 = a.x * inv, xn1 = a.y * inv;
        float m = waveMax(fmaxf(fabsf(xn0), fabsf(xn1)));
        float t = (m > 0.f) ? 127.f / m : 0.f;
        float sc = m * (1.0f / 127.f);                  // the s att1 will use
        int q0 = __float2int_rn(xn0 * t), q1 = __float2int_rn(xn1 * t);
        q0 = max(-127, min(127, q0));
        q1 = max(-127, min(127, q1));
        char2 pk; pk.x = (signed char)q0; pk.y = (signed char)q1;
        ((char2*)(xqi + (size_t)r * 256))[lane] = pk;
        // residual: ql = rn((xn - s*qh)*256/s), |xn - s*(qh+ql/256)| <= s/256
        float rq = (m > 0.f) ? 256.0f / sc : 0.f;
        int l0 = __float2int_rn((xn0 - sc * (float)q0) * rq);
        int l1 = __float2int_rn((xn1 - sc * (float)q1) * rq);
        l0 = max(-128, min(127, l0));
        l1 = max(-128, min(127, l1));
        char2 pl; pl.x = (signed char)l0; pl.y = (signed char)l1;
        ((char2*)(xqi + (size_t)r * 256 + 128))[lane] = pl;
        float asum = waveSum((float)(abs(q0) + abs(q1)));
        float axn  = waveSum(fabsf(xn0) + fabsf(xn1));
        if (lane == 0) {
            // P = 0.5*sum|qh| + 32 (e*f term) + 1 slop for f32 eval of the bound
            meta[r] = make_float4(sc, 0.5f * asum + 33.0f, axn, 0.0f);
            nrm[r] = nr;
            deg[r] = 0.0f;
            deg2[r] = 0.0f;
            counts[r] = 0;
            nrmsq[r] = 0.0f;
        }
    } else if (b < prepBlocks + 16) {
        // W1 B-fragments: w1x[((kb*16+ct)*64+lane)], elem j =
        // W1[kb*32 + (lane>>4)*8 + j][ct*16 + (lane&15)]
        int id = (b - prepBlocks) * 256 + tid;     // 0..4095
        int frag = id >> 6, lane = id & 63;
        int kb = frag >> 4, ct = frag & 15;
        int kbase = kb * 32 + (lane >> 4) * 8;
        int n = ct * 16 + (lane & 15);
        v8h v;
#pragma unroll
        for (int j = 0; j < 8; ++j)
            v[j] = (_Float16)W1f[(size_t)(kbase + j) * NHID + n];
        w1x[id] = v;
    } else {
        // W2 hi/lo B-fragments (f32-exact split), zero-padded cols >= NCLASS
        int id = (b - prepBlocks - 16) * 256 + tid;   // 0..3071
        int part = (id >= 1536) ? 1 : 0;
        int fid = id - part * 1536;
        int frag = fid >> 6, lane = fid & 63;
        int kb = frag / 3, ct = frag % 3;
        int kbase = kb * 32 + (lane >> 4) * 8;
        int n = ct * 16 + (lane & 15);
        v8h v;
#pragma unroll
        for (int j = 0; j < 8; ++j) {
            float wv = (n < NCLASS) ? W2f[(size_t)(kbase + j) * NCLASS + n] : 0.0f;
            _Float16 hi = (_Float16)wv;
            v[j] = part ? (_Float16)(wv - (float)hi) : hi;
        }
        w2x[id] = v;
    }
}

// ---- att1 v5: 16 edges/wave (4-lane groups). int8 screen + int8-residual
//      confirm (interleaved rows) + rare f32 fallback. Decisions identical. ----
__global__ void k_att1(const float* __restrict__ xf,
                       const signed char* __restrict__ xqi,
                       const float4* __restrict__ meta,
                       const int* __restrict__ row, const int* __restrict__ col,
                       const float* __restrict__ nrm,
                       float* __restrict__ w1, float* __restrict__ deg,
                       int* __restrict__ counts, int E) {
    int wid = (blockIdx.x * blockDim.x + threadIdx.x) >> 6;
    int lane = threadIdx.x & 63;
    int l4 = lane & 3;
    int e = wid * 16 + (lane >> 2);
    if (e >= E) return;
    int r = row[e], c = col[e];
    const int4* qra = (const int4*)(xqi + (size_t)r * 256);
    const int4* qca = (const int4*)(xqi + (size_t)c * 256);
    int4 qa0 = qra[l4 * 2], qa1 = qra[l4 * 2 + 1];
    int4 qb0 = qca[l4 * 2], qb1 = qca[l4 * 2 + 1];
    int d = 0;
    d = dot4acc(qa0.x, qb0.x, d); d = dot4acc(qa0.y, qb0.y, d);
    d = dot4acc(qa0.z, qb0.z, d); d = dot4acc(qa0.w, qb0.w, d);
    d = dot4acc(qa1.x, qb1.x, d); d = dot4acc(qa1.y, qb1.y, d);
    d = dot4acc(qa1.z, qb1.z, d); d = dot4acc(qa1.w, qb1.w, d);
    d += __shfl_xor(d, 1, 64);
    d += __shfl_xor(d, 2, 64);
    float4 mr = meta[r], mc = meta[c];
    float ub = mr.x * mc.x * ((float)d + mr.y + mc.y);   // >= dot(xn), worst-case
    float sims = 0.0f;
    bool alive = (ub >= THRESH - 1e-5f);
    if (alive) {
        const int4* lra = (const int4*)(xqi + (size_t)r * 256 + 128);
        const int4* lca = (const int4*)(xqi + (size_t)c * 256 + 128);
        int4 la0 = lra[l4 * 2], la1 = lra[l4 * 2 + 1];
        int4 lb0 = lca[l4 * 2], lb1 = lca[l4 * 2 + 1];
        int dll = 0, dx = 0;
        dll = dot4acc(la0.x, lb0.x, dll); dll = dot4acc(la0.y, lb0.y, dll);
        dll = dot4acc(la0.z, lb0.z, dll); dll = dot4acc(la0.w, lb0.w, dll);
        dll = dot4acc(la1.x, lb1.x, dll); dll = dot4acc(la1.y, lb1.y, dll);
        dll = dot4acc(la1.z, lb1.z, dll); dll = dot4acc(la1.w, lb1.w, dll);
        dx = dot4acc(qa0.x, lb0.x, dx); dx = dot4acc(qa0.y, lb0.y, dx);
        dx = dot4acc(qa0.z, lb0.z, dx); dx = dot4acc(qa0.w, lb0.w, dx);
        dx = dot4acc(qa1.x, lb1.x, dx); dx = dot4acc(qa1.y, lb1.y, dx);
        dx = dot4acc(qa1.z, lb1.z, dx); dx = dot4acc(qa1.w, lb1.w, dx);
        dx = dot4acc(la0.x, qb0.x, dx); dx = dot4acc(la0.y, qb0.y, dx);
        dx = dot4acc(la0.z, qb0.z, dx); dx = dot4acc(la0.w, qb0.w, dx);
        dx = dot4acc(la1.x, qb1.x, dx); dx = dot4acc(la1.y, qb1.y, dx);
        dx = dot4acc(la1.z, qb1.z, dx); dx = dot4acc(la1.w, qb1.w, dx);
        int conf = dx * 256 + dll;                 // per-lane <= ~267M, 4-lane sum < 2^31
        conf += __shfl_xor(conf, 1, 64);
        conf += __shfl_xor(conf, 2, 64);
        float ss = mr.x * mc.x;
        sims = ss * ((float)d + (float)conf * (1.0f / 65536.f));
        float errB = (mr.x * mc.z + mc.x * mr.z) * (1.0f / 256.f) + ss * 0.01f + 2e-5f;
        if (__builtin_expect(fabsf(sims - THRESH) < errB, 0)) {
            const float4* fr = (const float4*)(xf + (size_t)r * NFEAT);
            const float4* fc = (const float4*)(xf + (size_t)c * NFEAT);
            float s2 = 0.f;
#pragma unroll
            for (int j = 0; j < 8; ++j) {
                float4 av = fr[l4 + 4 * j], bv = fc[l4 + 4 * j];
                s2 += av.x * bv.x + av.y * bv.y + av.z * bv.z + av.w * bv.w;
            }
            s2 += __shfl_xor(s2, 1, 64);
            s2 += __shfl_xor(s2, 2, 64);
            sims = s2 / (nrm[r] * nrm[c]);
        }
    }
    if (l4 == 0) {
        float w = (alive && sims >= THRESH && r != c) ? sims : 0.0f;
        w1[e] = w;
        if (w != 0.0f) {
            unsafeAtomicAdd(&deg[r], w);
            atomicAdd(&counts[r], 1);
        }
    }
}

// ---- scan: per-block local exclusive scan (scan1) + block-sum scan (scan2).
//      Global offset bsum[r>>8] is applied inline by fill/gather/att2 (scan3
//      launch removed; identical integer arithmetic). ----
__global__ __launch_bounds__(256) void k_scan1(const int* __restrict__ counts,
                                               int* __restrict__ rowptr,
                                               int* __restrict__ bsum, int N) {
    __shared__ int tmp[256];
    int t = threadIdx.x, i = blockIdx.x * 256 + t;
    int v = (i < N) ? counts[i] : 0;
    tmp[t] = v;
    __syncthreads();
    for (int off = 1; off < 256; off <<= 1) {
        int add = (t >= off) ? tmp[t - off] : 0;
        __syncthreads();
        tmp[t] += add;
        __syncthreads();
    }
    if (i < N) rowptr[i] = tmp[t] - v;
    if (t == 255) bsum[blockIdx.x] = tmp[t];
}

__global__ __launch_bounds__(512) void k_scan2(int* __restrict__ bsum, int nb) {
    __shared__ int tmp[512];
    int t = threadIdx.x;
    int v = (t < nb) ? bsum[t] : 0;
    tmp[t] = v;
    __syncthreads();
    for (int off = 1; off < 512; off <<= 1) {
        int add = (t >= off) ? tmp[t - off] : 0;
        __syncthreads();
        tmp[t] += add;
        __syncthreads();
    }
    if (t < nb) bsum[t] = tmp[t] - v;
}

// ---- fill CSR: pos = local_scan + ticket + bsum[r>>8] (scan3 folded in) ----
__global__ void k_fill(const int* __restrict__ row, const int* __restrict__ col,
                       const float* __restrict__ wbuf, const float* __restrict__ deg,
                       int* __restrict__ rowptr, const int* __restrict__ bsum,
                       int2* __restrict__ edata, int* __restrict__ esrc, int E) {
    int e = blockIdx.x * blockDim.x + threadIdx.x;
    if (e >= E) return;
    float w = wbuf[e];
    if (w == 0.0f) return;
    int r = row[e], c = col[e];
    float dr = 1.0f / sqrtf(1.0f + deg[r]);
    float dc = 1.0f / sqrtf(1.0f + deg[c]);
    float nm = dr * w * dc;
    int pos = atomicAdd(&rowptr[r], 1) + bsum[r >> 8];
    edata[pos] = make_int2(c, __float_as_int(nm));
    esrc[pos] = r;
}

// ---- gather1 v4: 8-lane group per node; start = rowptr + bsum - cnt ----
__global__ void k_gather1(const float* __restrict__ xf, const int* __restrict__ rowptr,
                          const int* __restrict__ bsum,
                          const int* __restrict__ counts, const float* __restrict__ deg,
                          const int2* __restrict__ edata, float* __restrict__ xagg, int N) {
    int tid = blockIdx.x * blockDim.x + threadIdx.x;
    int r = tid >> 3;
    int l = tid & 7;
    if (r >= N) return;
    int cnt = counts[r];
    int start = rowptr[r] + bsum[r >> 8] - cnt;
    float d = 1.0f / sqrtf(1.0f + deg[r]);
    float dd = d * d;
    const float4* xr = (const float4*)(xf + (size_t)r * NFEAT) + l * 4;
    float4 c0, c1, c2, c3;
    {
        float4 a0 = xr[0], a1 = xr[1], a2 = xr[2], a3 = xr[3];
        c0 = make_float4(dd * a0.x, dd * a0.y, dd * a0.z, dd * a0.w);
        c1 = make_float4(dd * a1.x, dd * a1.y, dd * a1.z, dd * a1.w);
        c2 = make_float4(dd * a2.x, dd * a2.y, dd * a2.z, dd * a2.w);
        c3 = make_float4(dd * a3.x, dd * a3.y, dd * a3.z, dd * a3.w);
    }
    for (int k = 0; k < cnt; ++k) {
        int2 ed = edata[start + k];
        float nm = __int_as_float(ed.y);
        const float4* xc = (const float4*)(xf + (size_t)ed.x * NFEAT) + l * 4;
        float4 b0 = xc[0], b1 = xc[1], b2 = xc[2], b3 = xc[3];
        c0.x += nm * b0.x; c0.y += nm * b0.y; c0.z += nm * b0.z; c0.w += nm * b0.w;
        c1.x += nm * b1.x; c1.y += nm * b1.y; c1.z += nm * b1.z; c1.w += nm * b1.w;
        c2.x += nm * b2.x; c2.y += nm * b2.y; c2.z += nm * b2.z; c2.w += nm * b2.w;
        c3.x += nm * b3.x; c3.y += nm * b3.y; c3.z += nm * b3.z; c3.w += nm * b3.w;
    }
    float4* xo = (float4*)(xagg + (size_t)r * NFEAT) + l * 4;
    xo[0] = c0; xo[1] = c1; xo[2] = c2; xo[3] = c3;
}

// ---- gemm1h v8 (MFMA): h = relu(xagg @ W1 + b1); B-frags resident in LDS ----
__global__ __launch_bounds__(256) void k_gemm1h(const float* __restrict__ xagg,
                                                const v8h* __restrict__ w1x,
                                                const float* __restrict__ b1f,
                                                __half* __restrict__ hh16,
                                                float* __restrict__ nrmsq, int N) {
    __shared__ __half2 xsh[64][68];   // A tile: 64 nodes x 64 half2 (+4 pad) = 17.4 KB
    __shared__ v8h bsh[4][8][64];     // B frags for this col-half: 32 KB
    int tid = threadIdx.x;
    int ch = blockIdx.x & 1;          // column half: cols [ch*128, ch*128+128)
    int stripe = blockIdx.x >> 1;

#pragma unroll
    for (int it = 0; it < 8; ++it) {
        int id = it * 256 + tid;               // 0..2047
        int lane = id & 63, fr = id >> 6;      // fr 0..31
        int kb = fr >> 3, ctl = fr & 7;
        bsh[kb][ctl][lane] = w1x[(size_t)(kb * 16 + ch * 8 + ctl) * 64 + lane];
    }

    int w = tid >> 6, lane = tid & 63;
    int c = lane & 15, q = lane >> 4;
    int nb = w * 16;                  // wave's node base within tile

    int T = (N + 63) >> 6;
    for (int t = stripe; t < T; t += NSTRIPE) {
        int i0 = t * 64;
        __syncthreads();              // xsh free of previous tile's readers (+bsh ready)

#pragma unroll
        for (int it = 0; it < 16; ++it) {
            int idx = it * 256 + tid;          // 4096 half2
            int n = idx >> 6, kq = idx & 63;
            int i = i0 + n;
            float2 v = make_float2(0.f, 0.f);
            if (i < N) v = ((const float2*)(xagg + (size_t)i * NFEAT))[kq];
            xsh[n][kq] = __floats2half2_rn(v.x, v.y);
        }
        __syncthreads();

        f32x4 acc[8];
#pragma unroll
        for (int ct = 0; ct < 8; ++ct) acc[ct] = (f32x4){0.f, 0.f, 0.f, 0.f};

#pragma unroll
        for (int kb = 0; kb < 4; ++kb) {
            v8h a = *((const v8h*)&xsh[nb + c][kb * 16 + q * 4]);
#pragma unroll
            for (int ctl = 0; ctl < 8; ++ctl) {
                acc[ctl] = __builtin_amdgcn_mfma_f32_16x16x32_f16(
                    a, bsh[kb][ctl][lane], acc[ctl], 0, 0, 0);
            }
        }

        float s2[4] = {0.f, 0.f, 0.f, 0.f};
        bool full = (i0 + 64 <= N);
#pragma unroll
        for (int ctl = 0; ctl < 8; ++ctl) {
            int n = (ch * 8 + ctl) * 16 + c;
            float bias = b1f[n];
            f32x4 d = acc[ctl];
#pragma unroll
            for (int reg = 0; reg < 4; ++reg) {
                int node = i0 + nb + q * 4 + reg;   // D row = q*4+reg
                float v = fmaxf(d[reg] + bias, 0.f);
                s2[reg] += v * v;
                if (full || node < N) hh16[(size_t)node * NHID + n] = __float2half(v);
            }
        }
#pragma unroll
        for (int off = 1; off < 16; off <<= 1) {
#pragma unroll
            for (int reg = 0; reg < 4; ++reg) s2[reg] += __shfl_xor(s2[reg], off, 64);
        }
        if (c == 0) {
            int base = i0 + nb + q * 4;
#pragma unroll
            for (int reg = 0; reg < 4; ++reg)
                if (base + reg < N) unsafeAtomicAdd(&nrmsq[base + reg], s2[reg]);
        }
    }
}

// ---- l2fused: gemm2m role (blocks [0,gemmBlocks)) + att2e role (rest) ----
__global__ __launch_bounds__(256) void k_l2fused(
        // gemm2m args
        const __half2* __restrict__ hh, const v8h* __restrict__ w2x,
        float* __restrict__ g,
        // att2e args
        const float* __restrict__ xagg, const float* __restrict__ W1f,
        const float* __restrict__ b1f, const int* __restrict__ esrc,
        const int2* __restrict__ edata, const float* __restrict__ nrmsq,
        const int* __restrict__ etot, const int* __restrict__ ebs,
        float* __restrict__ w2csr, float* __restrict__ deg2,
        int gemmBlocks, int N) {
    __shared__ __half2 hs[64][NHID / 2 + 4];   // 33 KB (gemm role only)
    int tid = threadIdx.x;
    if ((int)blockIdx.x < gemmBlocks) {
        // ---------------- gemm2m role: g = h @ W2 (MFMA, hi/lo W2) ----------------
        int i0 = blockIdx.x * 64;
#pragma unroll
        for (int it = 0; it < 8; ++it) {
            int idx = it * 256 + tid;
            int n = idx >> 5, kq = idx & 31;     // row n, 16B-chunk kq (32 per row)
            int i = i0 + n;
            uint4 v = make_uint4(0u, 0u, 0u, 0u);
            if (i < N) v = ((const uint4*)(hh + (size_t)i * (NHID / 2)))[kq];
            *((uint4*)&hs[n][kq * 4]) = v;
        }
        __syncthreads();

        int w = tid >> 6, lane = tid & 63;
        int c = lane & 15, q = lane >> 4;
        int nb = w * 16;

        f32x4 acc[3];
#pragma unroll
        for (int t = 0; t < 3; ++t) acc[t] = (f32x4){0.f, 0.f, 0.f, 0.f};

#pragma unroll
        for (int kb = 0; kb < 8; ++kb) {
            v8h a = *((const v8h*)&hs[nb + c][kb * 16 + q * 4]);
            const v8h* bh = w2x + (size_t)(kb * 3) * 64 + lane;   // hi frags
            const v8h* bl = bh + 1536;                            // lo frags
#pragma unroll
            for (int ct = 0; ct < 3; ++ct) {
                acc[ct] = __builtin_amdgcn_mfma_f32_16x16x32_f16(a, bh[ct * 64], acc[ct], 0, 0, 0);
                acc[ct] = __builtin_amdgcn_mfma_f32_16x16x32_f16(a, bl[ct * 64], acc[ct], 0, 0, 0);
            }
        }

        bool full = (i0 + 64 <= N);
#pragma unroll
        for (int ct = 0; ct < 3; ++ct) {
            int cls = ct * 16 + c;
            if (cls < NCLASS) {
                f32x4 d = acc[ct];
#pragma unroll
                for (int reg = 0; reg < 4; ++reg) {
                    int node = i0 + nb + q * 4 + reg;   // D row = q*4+reg
                    if (full || node < N) g[(size_t)node * NCLASS + cls] = d[reg];
                }
            }
        }
    } else {
        // ---------------- att2e role: 8 CSR entries/wave, grid-stride ----------------
        int lane = tid & 63;
        int l8 = lane & 7, gr8 = lane >> 3;
        int nb2 = gridDim.x - gemmBlocks;
        int wid0 = (((int)blockIdx.x - gemmBlocks) * 256 + tid) >> 6;
        int step = (nb2 * 256) >> 3;            // waves-in-role * 8 edges
        int total = *etot + *ebs;               // = last local end + last block offset
        for (int base = wid0 * 8; base < total; base += step) {
            int pos = base + gr8;
            bool active = (pos < total);
            int r = 0, c = 0;
            float sims = 0.f, inv = 0.f;
            if (active) {
                r = esrc[pos];
                c = edata[pos].x;
                const uint4* hr4 = (const uint4*)(hh + (size_t)r * (NHID / 2));
                const uint4* hc4 = (const uint4*)(hh + (size_t)c * (NHID / 2));
                float s = 0.f;
#pragma unroll
                for (int j = 0; j < 4; ++j) {
                    uint4 a = hr4[l8 + 8 * j];
                    uint4 b = hc4[l8 + 8 * j];
                    s = dot2acc(a.x, b.x, s); s = dot2acc(a.y, b.y, s);
                    s = dot2acc(a.z, b.z, s); s = dot2acc(a.w, b.w, s);
                }
                s += __shfl_xor(s, 1, 64);
                s += __shfl_xor(s, 2, 64);
                s += __shfl_xor(s, 4, 64);
                float nr = fmaxf(sqrtf(nrmsq[r]), FEPS);
                float nc = fmaxf(sqrtf(nrmsq[c]), FEPS);
                inv = 1.0f / (nr * nc);
                sims = s * inv;
            }
            unsigned long long gm =
                __ballot(active && l8 == 0 && fabsf(sims - THRESH) < GUARD2);
            while (gm) {
                int src = __ffsll(gm) - 1;
                gm &= gm - 1;
                int rr = __shfl(r, src, 64);
                int cc = __shfl(c, src, 64);
                float invv = __shfl(inv, src, 64);
                int j0 = lane * 4;              // 64 lanes x 4 cols = 256
                float aR[4], aC[4];
#pragma unroll
                for (int q = 0; q < 4; ++q) { aR[q] = b1f[j0 + q]; aC[q] = b1f[j0 + q]; }
                const float* xr = xagg + (size_t)rr * NFEAT;
                const float* xc = xagg + (size_t)cc * NFEAT;
                for (int kk = 0; kk < NFEAT; ++kk) {
                    float vr = xr[kk], vc = xc[kk];   // wave-broadcast loads
                    float4 wv = *((const float4*)(W1f + (size_t)kk * NHID + j0));
                    aR[0] += vr * wv.x; aC[0] += vc * wv.x;
                    aR[1] += vr * wv.y; aC[1] += vc * wv.y;
                    aR[2] += vr * wv.z; aC[2] += vc * wv.z;
                    aR[3] += vr * wv.w; aC[3] += vc * wv.w;
                }
                float dp = 0.f;
#pragma unroll
                for (int q = 0; q < 4; ++q)
                    dp += fmaxf(aR[q], 0.f) * fmaxf(aC[q], 0.f);
                float se = waveSum(dp) * invv;
                if (lane == src) sims = se;
            }
            if (active && l8 == 0) {
                float w2 = (sims >= THRESH) ? sims : 0.f;
                w2csr[pos] = w2;
                if (w2 != 0.f) unsafeAtomicAdd(&deg2[r], w2);
            }
        }
    }
}

// ---- gather2 v5: 8-lane group per node; dinv2 inline; start via bsum ----
__global__ void k_gather2(const float* __restrict__ g, const int* __restrict__ rowptr,
                          const int* __restrict__ bsum,
                          const int* __restrict__ counts, const float* __restrict__ deg2,
                          const float* __restrict__ b2f, const int2* __restrict__ edata,
                          const float* __restrict__ w2csr, float* __restrict__ out, int N) {
    int tid = blockIdx.x * blockDim.x + threadIdx.x;
    int r = tid >> 3;
    int l = tid & 7;
    if (r >= N) return;
    int cnt = counts[r];
    int start = rowptr[r] + bsum[r >> 8] - cnt;
    float dr = 1.0f / sqrtf(1.0f + deg2[r]);
    float drr = dr * dr;
    const float* gr = g + (size_t)r * NCLASS;
    float acc[5];
#pragma unroll
    for (int q = 0; q < 5; ++q) acc[q] = drr * gr[l + 8 * q] + b2f[l + 8 * q];
    for (int k = 0; k < cnt; ++k) {
        int2 ed = edata[start + k];
        float w2 = w2csr[start + k];
        float dc = 1.0f / sqrtf(1.0f + deg2[ed.x]);
        float f = dr * w2 * dc;
        const float* gc = g + (size_t)ed.x * NCLASS;
#pragma unroll
        for (int q = 0; q < 5; ++q) acc[q] += f * gc[l + 8 * q];
    }
    float* po = out + (size_t)r * NCLASS;
#pragma unroll
    for (int q = 0; q < 5; ++q) po[l + 8 * q] = acc[q];
}

extern "C" void kernel_launch(void* const* d_in, const int* in_sizes, int n_in,
                              void* d_out, int out_size, void* d_ws, size_t ws_size,
                              hipStream_t stream) {
    const float* x  = (const float*)d_in[0];
    const int* row  = (const int*)d_in[1];
    const int* col  = (const int*)d_in[2];
    const float* W1 = (const float*)d_in[3];
    const float* b1 = (const float*)d_in[4];
    const float* W2 = (const float*)d_in[5];
    const float* b2 = (const float*)d_in[6];
    float* out = (float*)d_out;
    const int N = in_sizes[0] / NFEAT;
    const int E = in_sizes[1];

    // ---- workspace layout ----
    char* ws = (char*)d_ws;
    size_t off = 0;
    auto alloc = [&](size_t bytes) {
        char* p = ws + off;
        off += (bytes + 255) & ~(size_t)255;
        return p;
    };
    float*   xagg   = (float*)alloc((size_t)N * NFEAT * 4);   // live thru att2e
    __half2* hh     = (__half2*)alloc((size_t)N * NHID * 2);  // fp16 h mirror
    float*   w1buf  = (float*)alloc((size_t)E * 4);
    float*   w2csr  = (float*)alloc((size_t)E * 4);
    int2*    edata  = (int2*)alloc((size_t)E * 8);
    int*     esrc   = (int*)alloc((size_t)E * 4);             // CSR source nodes
    float*   nrm    = (float*)alloc((size_t)N * 4);           // layer-1 norms (att1 guard)
    float*   deg    = (float*)alloc((size_t)N * 4);           // degsum layer 1
    int*     counts = (int*)alloc((size_t)N * 4);
    int*     rowptr = (int*)alloc((size_t)N * 4);
    int*     bsum   = (int*)alloc(512 * 4);
    v8h*     w1x    = (v8h*)alloc(4096 * 16);                 // W1 B-fragments (64 KB)
    v8h*     w2x    = (v8h*)alloc(3072 * 16);                 // W2 hi/lo B-fragments (48 KB)
    float*   nrmsq  = (float*)alloc((size_t)N * 4);           // h row sum-of-squares
    float*   deg2   = (float*)alloc((size_t)N * 4);           // layer-2 degree sums
    // int8 screen table overlays xagg (xagg written only later, by k_gather1):
    // [xqi: N*256B interleaved qh|ql][meta: N*16B] = 27.2 MB < 51.2 MB
    signed char* xqi = (signed char*)xagg;
    float4*  meta    = (float4*)(xqi + (size_t)N * 256);
    // dedicated g (so att2e's guard can read xagg while gemm2m writes g):
    size_t gBytes = ((size_t)N * NCLASS * 4 + 255) & ~(size_t)255;
    bool fused = (off + gBytes <= ws_size);
    float* g = fused ? (float*)alloc(gBytes) : xagg;   // fallback: overlay

    const int e16Blocks = (E + 63) / 64;  // 16 edges/wave, 4 waves/block
    const int eBlocks1 = (E + 255) / 256;
    const int nBlocks4 = (N + 3) / 4;
    const int nBlocks8 = (N + 31) / 32;   // 8-lane-group kernels (8 nodes/wave)
    const int scanB    = (N + 255) / 256;
    const int gemmB    = (N + 63) / 64;

    // ---- layer 1 ----
    k_prepw<<<nBlocks4 + 28, 256, 0, stream>>>(x, xqi, meta, nrm, deg, deg2,
                                               counts, nrmsq, W1, w1x, W2, w2x,
                                               N, nBlocks4);
    k_att1<<<e16Blocks, 256, 0, stream>>>(x, xqi, meta, row, col, nrm, w1buf, deg,
                                          counts, E);
    k_scan1<<<scanB, 256, 0, stream>>>(counts, rowptr, bsum, N);
    k_scan2<<<1, 512, 0, stream>>>(bsum, scanB);
    k_fill<<<eBlocks1, 256, 0, stream>>>(row, col, w1buf, deg, rowptr, bsum, edata,
                                         esrc, E);
    k_gather1<<<nBlocks8, 256, 0, stream>>>(x, rowptr, bsum, counts, deg, edata,
                                            xagg, N);
    k_gemm1h<<<2 * NSTRIPE, 256, 0, stream>>>(xagg, w1x, b1, (__half*)hh, nrmsq, N);

    // ---- layer 2 ----
    k_l2fused<<<gemmB + 4096, 256, 0, stream>>>(hh, w2x, g, xagg, W1, b1, esrc,
                                                edata, nrmsq, rowptr + (N - 1),
                                                bsum + ((N - 1) >> 8),
                                                w2csr, deg2, gemmB, N);
    k_gather2<<<nBlocks8, 256, 0, stream>>>(g, rowptr, bsum, counts, deg2, b2, edata,
                                            w2csr, out, N);
}

// Round 14
// 296.326 us; speedup vs baseline: 6.2443x; 1.0207x over previous
//
#include <hip/hip_runtime.h>
#include <hip/hip_bf16.h>
#include <hip/hip_fp16.h>

#define NFEAT 128
#define NHID  256
#define NCLASS 40
#define THRESH 0.1f
#define FEPS   1e-8f
#define GUARD2 4e-3f
#define NSTRIPE 384   // gemm1h node-tile stripes (one block does BOTH col-halves)

typedef _Float16 v2h __attribute__((ext_vector_type(2)));
typedef _Float16 v8h __attribute__((ext_vector_type(8)));
typedef float f32x4 __attribute__((ext_vector_type(4)));

// fdot2: s += dot(2xfp16, 2xfp16) in one VALU op where available
__device__ __forceinline__ float dot2acc(unsigned int a, unsigned int b, float s) {
#if __has_builtin(__builtin_amdgcn_fdot2)
    return __builtin_amdgcn_fdot2(__builtin_bit_cast(v2h, a),
                                  __builtin_bit_cast(v2h, b), s, false);
#else
    float2 fa = __half22float2(__builtin_bit_cast(__half2, a));
    float2 fb = __half22float2(__builtin_bit_cast(__half2, b));
    return s + fa.x * fb.x + fa.y * fb.y;
#endif
}

// sdot4: acc += dot(4x int8, 4x int8) — v_dot4_i32_i8
__device__ __forceinline__ int dot4acc(int a, int b, int acc) {
#if __has_builtin(__builtin_amdgcn_sdot4)
    return __builtin_amdgcn_sdot4(a, b, acc, false);
#else
#pragma unroll
    for (int k = 0; k < 4; ++k) {
        int av = (a << (24 - 8 * k)) >> 24;
        int bv = (b << (24 - 8 * k)) >> 24;
        acc += av * bv;
    }
    return acc;
#endif
}

__device__ __forceinline__ float waveSum(float v) {
#pragma unroll
    for (int off = 32; off > 0; off >>= 1) v += __shfl_xor(v, off, 64);
    return v;
}

__device__ __forceinline__ float waveMax(float v) {
#pragma unroll
    for (int off = 32; off > 0; off >>= 1) v = fmaxf(v, __shfl_xor(v, off, 64));
    return v;
}

// ---- prep + W-fragment build fused. int8 tables INTERLEAVED per row:
//      xqi[r*256 .. +127] = qh, [r*256+128 .. +255] = ql ----
__global__ void k_prepw(const float* __restrict__ x,
                        signed char* __restrict__ xqi,
                        float4* __restrict__ meta,
                        float* __restrict__ nrm, float* __restrict__ deg,
                        float* __restrict__ deg2,
                        int* __restrict__ counts, float* __restrict__ nrmsq,
                        const float* __restrict__ W1f, v8h* __restrict__ w1x,
                        const float* __restrict__ W2f, v8h* __restrict__ w2x,
                        int N, int prepBlocks) {
    int b = blockIdx.x;
    int tid = threadIdx.x;
    if (b < prepBlocks) {
        int r = (b * 256 + tid) >> 6;
        int lane = tid & 63;
        if (r >= N) return;
        float2 a = ((const float2*)(x + (size_t)r * NFEAT))[lane];
        float s = waveSum(a.x * a.x + a.y * a.y);
        float nr = fmaxf(sqrtf(s), FEPS);
        float inv = 1.0f / nr;
        float xn0 = a.x * inv, xn1 = a.y * inv;
        float m = waveMax(fmaxf(fabsf(xn0), fabsf(xn1)));
        float t = (m > 0.f) ? 127.f / m : 0.f;
        float sc = m * (1.0f / 127.f);                  // the s att1 will use
        int q0 = __float2int_rn(xn0 * t), q1 = __float2int_rn(xn1 * t);
        q0 = max(-127, min(127, q0));
        q1 = max(-127, min(127, q1));
        char2 pk; pk.x = (signed char)q0; pk.y = (signed char)q1;
        ((char2*)(xqi + (size_t)r * 256))[lane] = pk;
        // residual: ql = rn((xn - s*qh)*256/s), |xn - s*(qh+ql/256)| <= s/256
        float rq = (m > 0.f) ? 256.0f / sc : 0.f;
        int l0 = __float2int_rn((xn0 - sc * (float)q0) * rq);
        int l1 = __float2int_rn((xn1 - sc * (float)q1) * rq);
        l0 = max(-128, min(127, l0));
        l1 = max(-128, min(127, l1));
        char2 pl; pl.x = (signed char)l0; pl.y = (signed char)l1;
        ((char2*)(xqi + (size_t)r * 256 + 128))[lane] = pl;
        float asum = waveSum((float)(abs(q0) + abs(q1)));
        float axn  = waveSum(fabsf(xn0) + fabsf(xn1));
        if (lane == 0) {
            // P = 0.5*sum|qh| + 32 (e*f term) + 1 slop for f32 eval of the bound
            meta[r] = make_float4(sc, 0.5f * asum + 33.0f, axn, 0.0f);
            nrm[r] = nr;
            deg[r] = 0.0f;
            deg2[r] = 0.0f;
            counts[r] = 0;
            nrmsq[r] = 0.0f;
        }
    } else if (b < prepBlocks + 16) {
        // W1 B-fragments: w1x[((kb*16+ct)*64+lane)], elem j =
        // W1[kb*32 + (lane>>4)*8 + j][ct*16 + (lane&15)]
        int id = (b - prepBlocks) * 256 + tid;     // 0..4095
        int frag = id >> 6, lane = id & 63;
        int kb = frag >> 4, ct = frag & 15;
        int kbase = kb * 32 + (lane >> 4) * 8;
        int n = ct * 16 + (lane & 15);
        v8h v;
#pragma unroll
        for (int j = 0; j < 8; ++j)
            v[j] = (_Float16)W1f[(size_t)(kbase + j) * NHID + n];
        w1x[id] = v;
    } else {
        // W2 hi/lo B-fragments (f32-exact split), zero-padded cols >= NCLASS
        int id = (b - prepBlocks - 16) * 256 + tid;   // 0..3071
        int part = (id >= 1536) ? 1 : 0;
        int fid = id - part * 1536;
        int frag = fid >> 6, lane = fid & 63;
        int kb = frag / 3, ct = frag % 3;
        int kbase = kb * 32 + (lane >> 4) * 8;
        int n = ct * 16 + (lane & 15);
        v8h v;
#pragma unroll
        for (int j = 0; j < 8; ++j) {
            float wv = (n < NCLASS) ? W2f[(size_t)(kbase + j) * NCLASS + n] : 0.0f;
            _Float16 hi = (_Float16)wv;
            v[j] = part ? (_Float16)(wv - (float)hi) : hi;
        }
        w2x[id] = v;
    }
}

// ---- att1 v5: 16 edges/wave (4-lane groups). int8 screen + int8-residual
//      confirm (interleaved rows) + rare f32 fallback. ----
__global__ void k_att1(const float* __restrict__ xf,
                       const signed char* __restrict__ xqi,
                       const float4* __restrict__ meta,
                       const int* __restrict__ row, const int* __restrict__ col,
                       const float* __restrict__ nrm,
                       float* __restrict__ w1, float* __restrict__ deg,
                       int* __restrict__ counts, int E) {
    int wid = (blockIdx.x * blockDim.x + threadIdx.x) >> 6;
    int lane = threadIdx.x & 63;
    int l4 = lane & 3;
    int e = wid * 16 + (lane >> 2);
    if (e >= E) return;
    int r = row[e], c = col[e];
    const int4* qra = (const int4*)(xqi + (size_t)r * 256);
    const int4* qca = (const int4*)(xqi + (size_t)c * 256);
    int4 qa0 = qra[l4 * 2], qa1 = qra[l4 * 2 + 1];
    int4 qb0 = qca[l4 * 2], qb1 = qca[l4 * 2 + 1];
    int d = 0;
    d = dot4acc(qa0.x, qb0.x, d); d = dot4acc(qa0.y, qb0.y, d);
    d = dot4acc(qa0.z, qb0.z, d); d = dot4acc(qa0.w, qb0.w, d);
    d = dot4acc(qa1.x, qb1.x, d); d = dot4acc(qa1.y, qb1.y, d);
    d = dot4acc(qa1.z, qb1.z, d); d = dot4acc(qa1.w, qb1.w, d);
    d += __shfl_xor(d, 1, 64);
    d += __shfl_xor(d, 2, 64);
    float4 mr = meta[r], mc = meta[c];
    float ub = mr.x * mc.x * ((float)d + mr.y + mc.y);   // >= dot(xn), worst-case
    float sims = 0.0f;
    bool alive = (ub >= THRESH - 1e-5f);
    if (alive) {
        const int4* lra = (const int4*)(xqi + (size_t)r * 256 + 128);
        const int4* lca = (const int4*)(xqi + (size_t)c * 256 + 128);
        int4 la0 = lra[l4 * 2], la1 = lra[l4 * 2 + 1];
        int4 lb0 = lca[l4 * 2], lb1 = lca[l4 * 2 + 1];
        int dll = 0, dx = 0;
        dll = dot4acc(la0.x, lb0.x, dll); dll = dot4acc(la0.y, lb0.y, dll);
        dll = dot4acc(la0.z, lb0.z, dll); dll = dot4acc(la0.w, lb0.w, dll);
        dll = dot4acc(la1.x, lb1.x, dll); dll = dot4acc(la1.y, lb1.y, dll);
        dll = dot4acc(la1.z, lb1.z, dll); dll = dot4acc(la1.w, lb1.w, dll);
        dx = dot4acc(qa0.x, lb0.x, dx); dx = dot4acc(qa0.y, lb0.y, dx);
        dx = dot4acc(qa0.z, lb0.z, dx); dx = dot4acc(qa0.w, lb0.w, dx);
        dx = dot4acc(qa1.x, lb1.x, dx); dx = dot4acc(qa1.y, lb1.y, dx);
        dx = dot4acc(qa1.z, lb1.z, dx); dx = dot4acc(qa1.w, lb1.w, dx);
        dx = dot4acc(la0.x, qb0.x, dx); dx = dot4acc(la0.y, qb0.y, dx);
        dx = dot4acc(la0.z, qb0.z, dx); dx = dot4acc(la0.w, qb0.w, dx);
        dx = dot4acc(la1.x, qb1.x, dx); dx = dot4acc(la1.y, qb1.y, dx);
        dx = dot4acc(la1.z, qb1.z, dx); dx = dot4acc(la1.w, qb1.w, dx);
        int conf = dx * 256 + dll;                 // per-lane <= ~267M, 4-lane sum < 2^31
        conf += __shfl_xor(conf, 1, 64);
        conf += __shfl_xor(conf, 2, 64);
        float ss = mr.x * mc.x;
        sims = ss * ((float)d + (float)conf * (1.0f / 65536.f));
        float errB = (mr.x * mc.z + mc.x * mr.z) * (1.0f / 256.f) + ss * 0.01f + 2e-5f;
        if (__builtin_expect(fabsf(sims - THRESH) < errB, 0)) {
            const float4* fr = (const float4*)(xf + (size_t)r * NFEAT);
            const float4* fc = (const float4*)(xf + (size_t)c * NFEAT);
            float s2 = 0.f;
#pragma unroll
            for (int j = 0; j < 8; ++j) {
                float4 av = fr[l4 + 4 * j], bv = fc[l4 + 4 * j];
                s2 += av.x * bv.x + av.y * bv.y + av.z * bv.z + av.w * bv.w;
            }
            s2 += __shfl_xor(s2, 1, 64);
            s2 += __shfl_xor(s2, 2, 64);
            sims = s2 / (nrm[r] * nrm[c]);
        }
    }
    if (l4 == 0) {
        float w = (alive && sims >= THRESH && r != c) ? sims : 0.0f;
        w1[e] = w;
        if (w != 0.0f) {
            unsafeAtomicAdd(&deg[r], w);
            atomicAdd(&counts[r], 1);
        }
    }
}

// ---- scan: local exclusive scan + block-sum scan; offset applied inline ----
__global__ __launch_bounds__(256) void k_scan1(const int* __restrict__ counts,
                                               int* __restrict__ rowptr,
                                               int* __restrict__ bsum, int N) {
    __shared__ int tmp[256];
    int t = threadIdx.x, i = blockIdx.x * 256 + t;
    int v = (i < N) ? counts[i] : 0;
    tmp[t] = v;
    __syncthreads();
    for (int off = 1; off < 256; off <<= 1) {
        int add = (t >= off) ? tmp[t - off] : 0;
        __syncthreads();
        tmp[t] += add;
        __syncthreads();
    }
    if (i < N) rowptr[i] = tmp[t] - v;
    if (t == 255) bsum[blockIdx.x] = tmp[t];
}

__global__ __launch_bounds__(512) void k_scan2(int* __restrict__ bsum, int nb) {
    __shared__ int tmp[512];
    int t = threadIdx.x;
    int v = (t < nb) ? bsum[t] : 0;
    tmp[t] = v;
    __syncthreads();
    for (int off = 1; off < 512; off <<= 1) {
        int add = (t >= off) ? tmp[t - off] : 0;
        __syncthreads();
        tmp[t] += add;
        __syncthreads();
    }
    if (t < nb) bsum[t] = tmp[t] - v;
}

// ---- fill CSR: pos = local_scan + ticket + bsum[r>>8] ----
__global__ void k_fill(const int* __restrict__ row, const int* __restrict__ col,
                       const float* __restrict__ wbuf, const float* __restrict__ deg,
                       int* __restrict__ rowptr, const int* __restrict__ bsum,
                       int2* __restrict__ edata, int* __restrict__ esrc, int E) {
    int e = blockIdx.x * blockDim.x + threadIdx.x;
    if (e >= E) return;
    float w = wbuf[e];
    if (w == 0.0f) return;
    int r = row[e], c = col[e];
    float dr = 1.0f / sqrtf(1.0f + deg[r]);
    float dc = 1.0f / sqrtf(1.0f + deg[c]);
    float nm = dr * w * dc;
    int pos = atomicAdd(&rowptr[r], 1) + bsum[r >> 8];
    edata[pos] = make_int2(c, __float_as_int(nm));
    esrc[pos] = r;
}

// ---- gather1 v5: 8-lane group per node. Writes f32 xagg (att2 guard) AND the
//      fp16 mirror xaggh (same __floats2half2_rn pairing gemm1h used -> h is
//      bit-identical; gemm1h now reads 25.6 MB fp16 once instead of 102 MB f32). ----
__global__ void k_gather1(const float* __restrict__ xf, const int* __restrict__ rowptr,
                          const int* __restrict__ bsum,
                          const int* __restrict__ counts, const float* __restrict__ deg,
                          const int2* __restrict__ edata, float* __restrict__ xagg,
                          __half2* __restrict__ xaggh, int N) {
    int tid = blockIdx.x * blockDim.x + threadIdx.x;
    int r = tid >> 3;
    int l = tid & 7;
    if (r >= N) return;
    int cnt = counts[r];
    int start = rowptr[r] + bsum[r >> 8] - cnt;
    float d = 1.0f / sqrtf(1.0f + deg[r]);
    float dd = d * d;
    const float4* xr = (const float4*)(xf + (size_t)r * NFEAT) + l * 4;
    float4 c0, c1, c2, c3;
    {
        float4 a0 = xr[0], a1 = xr[1], a2 = xr[2], a3 = xr[3];
        c0 = make_float4(dd * a0.x, dd * a0.y, dd * a0.z, dd * a0.w);
        c1 = make_float4(dd * a1.x, dd * a1.y, dd * a1.z, dd * a1.w);
        c2 = make_float4(dd * a2.x, dd * a2.y, dd * a2.z, dd * a2.w);
        c3 = make_float4(dd * a3.x, dd * a3.y, dd * a3.z, dd * a3.w);
    }
    for (int k = 0; k < cnt; ++k) {
        int2 ed = edata[start + k];
        float nm = __int_as_float(ed.y);
        const float4* xc = (const float4*)(xf + (size_t)ed.x * NFEAT) + l * 4;
        float4 b0 = xc[0], b1 = xc[1], b2 = xc[2], b3 = xc[3];
        c0.x += nm * b0.x; c0.y += nm * b0.y; c0.z += nm * b0.z; c0.w += nm * b0.w;
        c1.x += nm * b1.x; c1.y += nm * b1.y; c1.z += nm * b1.z; c1.w += nm * b1.w;
        c2.x += nm * b2.x; c2.y += nm * b2.y; c2.z += nm * b2.z; c2.w += nm * b2.w;
        c3.x += nm * b3.x; c3.y += nm * b3.y; c3.z += nm * b3.z; c3.w += nm * b3.w;
    }
    float4* xo = (float4*)(xagg + (size_t)r * NFEAT) + l * 4;
    xo[0] = c0; xo[1] = c1; xo[2] = c2; xo[3] = c3;
    union { uint4 u; __half2 h[4]; } p0, p1;
    p0.h[0] = __floats2half2_rn(c0.x, c0.y);
    p0.h[1] = __floats2half2_rn(c0.z, c0.w);
    p0.h[2] = __floats2half2_rn(c1.x, c1.y);
    p0.h[3] = __floats2half2_rn(c1.z, c1.w);
    p1.h[0] = __floats2half2_rn(c2.x, c2.y);
    p1.h[1] = __floats2half2_rn(c2.z, c2.w);
    p1.h[2] = __floats2half2_rn(c3.x, c3.y);
    p1.h[3] = __floats2half2_rn(c3.z, c3.w);
    uint4* ho = (uint4*)(xaggh + (size_t)r * (NFEAT / 2));
    ho[l * 2] = p0.u;
    ho[l * 2 + 1] = p1.u;
}

// ---- gemm1h v9 (MFMA): one block does BOTH col-halves per tile. A-tile staged
//      once from fp16 xaggh (no cvt); B-half (32 KB) re-staged from L2 per half.
//      xagg read traffic 102 MB f32 -> 25.6 MB fp16. LDS 49.4 KB, 3 blocks/CU. ----
__global__ __launch_bounds__(256) void k_gemm1h(const __half2* __restrict__ xaggh,
                                                const v8h* __restrict__ w1x,
                                                const float* __restrict__ b1f,
                                                __half* __restrict__ hh16,
                                                float* __restrict__ nrmsq, int N) {
    __shared__ __half2 xsh[64][68];   // A tile: 64 nodes x 64 half2 (+4 pad) = 17.4 KB
    __shared__ v8h bsh[4][8][64];     // B frags for CURRENT col-half: 32 KB
    int tid = threadIdx.x;
    int w = tid >> 6, lane = tid & 63;
    int c = lane & 15, q = lane >> 4;
    int nb = w * 16;                  // wave's node base within tile

    int T = (N + 63) >> 6;
    for (int t = blockIdx.x; t < T; t += NSTRIPE) {
        int i0 = t * 64;
        __syncthreads();              // previous tile's readers done (xsh + bsh)

        // stage A tile: 64 rows x 256 B = 1024 uint4, coalesced, no conversion
#pragma unroll
        for (int it = 0; it < 4; ++it) {
            int idx = it * 256 + tid;          // 0..1023
            int n = idx >> 4, kq = idx & 15;   // row n, 16B chunk kq (16 per row)
            int i = i0 + n;
            uint4 v = make_uint4(0u, 0u, 0u, 0u);
            if (i < N) v = ((const uint4*)(xaggh + (size_t)i * (NFEAT / 2)))[kq];
            *((uint4*)&xsh[n][kq * 4]) = v;
        }

#pragma unroll
        for (int ch = 0; ch < 2; ++ch) {
            if (ch == 1) __syncthreads();      // half-0 bsh reads complete
            // stage this half's W1 B-fragments (coalesced 16B copies from L2)
#pragma unroll
            for (int it = 0; it < 8; ++it) {
                int id = it * 256 + tid;               // 0..2047
                int lane2 = id & 63, fr = id >> 6;     // fr 0..31
                int kb = fr >> 3, ctl = fr & 7;
                bsh[kb][ctl][lane2] = w1x[(size_t)(kb * 16 + ch * 8 + ctl) * 64 + lane2];
            }
            __syncthreads();                   // xsh (ch==0) + bsh ready

            f32x4 acc[8];
#pragma unroll
            for (int ct = 0; ct < 8; ++ct) acc[ct] = (f32x4){0.f, 0.f, 0.f, 0.f};

#pragma unroll
            for (int kb = 0; kb < 4; ++kb) {
                // A-frag: row m=c, k = kb*32 + q*8 + j  ->  half2 col kb*16 + q*4
                v8h a = *((const v8h*)&xsh[nb + c][kb * 16 + q * 4]);
#pragma unroll
                for (int ctl = 0; ctl < 8; ++ctl) {
                    acc[ctl] = __builtin_amdgcn_mfma_f32_16x16x32_f16(
                        a, bsh[kb][ctl][lane], acc[ctl], 0, 0, 0);
                }
            }

            // epilogue: bias + ReLU, fp16 stores, partial row-norm -> atomic
            float s2[4] = {0.f, 0.f, 0.f, 0.f};
            bool full = (i0 + 64 <= N);
#pragma unroll
            for (int ctl = 0; ctl < 8; ++ctl) {
                int n = (ch * 8 + ctl) * 16 + c;
                float bias = b1f[n];
                f32x4 dv = acc[ctl];
#pragma unroll
                for (int reg = 0; reg < 4; ++reg) {
                    int node = i0 + nb + q * 4 + reg;   // D row = q*4+reg
                    float v = fmaxf(dv[reg] + bias, 0.f);
                    s2[reg] += v * v;
                    if (full || node < N) hh16[(size_t)node * NHID + n] = __float2half(v);
                }
            }
#pragma unroll
            for (int off = 1; off < 16; off <<= 1) {
#pragma unroll
                for (int reg = 0; reg < 4; ++reg) s2[reg] += __shfl_xor(s2[reg], off, 64);
            }
            if (c == 0) {
                int base = i0 + nb + q * 4;
#pragma unroll
                for (int reg = 0; reg < 4; ++reg)
                    if (base + reg < N) unsafeAtomicAdd(&nrmsq[base + reg], s2[reg]);
            }
        }
    }
}

// ---- l2fused: gemm2m role (blocks [0,gemmBlocks)) + att2e role (rest) ----
__global__ __launch_bounds__(256) void k_l2fused(
        // gemm2m args
        const __half2* __restrict__ hh, const v8h* __restrict__ w2x,
        float* __restrict__ g,
        // att2e args
        const float* __restrict__ xagg, const float* __restrict__ W1f,
        const float* __restrict__ b1f, const int* __restrict__ esrc,
        const int2* __restrict__ edata, const float* __restrict__ nrmsq,
        const int* __restrict__ etot, const int* __restrict__ ebs,
        float* __restrict__ w2csr, float* __restrict__ deg2,
        int gemmBlocks, int N) {
    __shared__ __half2 hs[64][NHID / 2 + 4];   // 33 KB (gemm role only)
    int tid = threadIdx.x;
    if ((int)blockIdx.x < gemmBlocks) {
        // ---------------- gemm2m role: g = h @ W2 (MFMA, hi/lo W2) ----------------
        int i0 = blockIdx.x * 64;
#pragma unroll
        for (int it = 0; it < 8; ++it) {
            int idx = it * 256 + tid;
            int n = idx >> 5, kq = idx & 31;     // row n, 16B-chunk kq (32 per row)
            int i = i0 + n;
            uint4 v = make_uint4(0u, 0u, 0u, 0u);
            if (i < N) v = ((const uint4*)(hh + (size_t)i * (NHID / 2)))[kq];
            *((uint4*)&hs[n][kq * 4]) = v;
        }
        __syncthreads();

        int w = tid >> 6, lane = tid & 63;
        int c = lane & 15, q = lane >> 4;
        int nb = w * 16;

        f32x4 acc[3];
#pragma unroll
        for (int t = 0; t < 3; ++t) acc[t] = (f32x4){0.f, 0.f, 0.f, 0.f};

#pragma unroll
        for (int kb = 0; kb < 8; ++kb) {
            v8h a = *((const v8h*)&hs[nb + c][kb * 16 + q * 4]);
            const v8h* bh = w2x + (size_t)(kb * 3) * 64 + lane;   // hi frags
            const v8h* bl = bh + 1536;                            // lo frags
#pragma unroll
            for (int ct = 0; ct < 3; ++ct) {
                acc[ct] = __builtin_amdgcn_mfma_f32_16x16x32_f16(a, bh[ct * 64], acc[ct], 0, 0, 0);
                acc[ct] = __builtin_amdgcn_mfma_f32_16x16x32_f16(a, bl[ct * 64], acc[ct], 0, 0, 0);
            }
        }

        bool full = (i0 + 64 <= N);
#pragma unroll
        for (int ct = 0; ct < 3; ++ct) {
            int cls = ct * 16 + c;
            if (cls < NCLASS) {
                f32x4 d = acc[ct];
#pragma unroll
                for (int reg = 0; reg < 4; ++reg) {
                    int node = i0 + nb + q * 4 + reg;   // D row = q*4+reg
                    if (full || node < N) g[(size_t)node * NCLASS + cls] = d[reg];
                }
            }
        }
    } else {
        // ---------------- att2e role: 8 CSR entries/wave, grid-stride ----------------
        int lane = tid & 63;
        int l8 = lane & 7, gr8 = lane >> 3;
        int nb2 = gridDim.x - gemmBlocks;
        int wid0 = (((int)blockIdx.x - gemmBlocks) * 256 + tid) >> 6;
        int step = (nb2 * 256) >> 3;            // waves-in-role * 8 edges
        int total = *etot + *ebs;               // = last local end + last block offset
        for (int base = wid0 * 8; base < total; base += step) {
            int pos = base + gr8;
            bool active = (pos < total);
            int r = 0, c = 0;
            float sims = 0.f, inv = 0.f;
            if (active) {
                r = esrc[pos];
                c = edata[pos].x;
                const uint4* hr4 = (const uint4*)(hh + (size_t)r * (NHID / 2));
                const uint4* hc4 = (const uint4*)(hh + (size_t)c * (NHID / 2));
                float s = 0.f;
#pragma unroll
                for (int j = 0; j < 4; ++j) {
                    uint4 a = hr4[l8 + 8 * j];
                    uint4 b = hc4[l8 + 8 * j];
                    s = dot2acc(a.x, b.x, s); s = dot2acc(a.y, b.y, s);
                    s = dot2acc(a.z, b.z, s); s = dot2acc(a.w, b.w, s);
                }
                s += __shfl_xor(s, 1, 64);
                s += __shfl_xor(s, 2, 64);
                s += __shfl_xor(s, 4, 64);
                float nr = fmaxf(sqrtf(nrmsq[r]), FEPS);
                float nc = fmaxf(sqrtf(nrmsq[c]), FEPS);
                inv = 1.0f / (nr * nc);
                sims = s * inv;
            }
            unsigned long long gm =
                __ballot(active && l8 == 0 && fabsf(sims - THRESH) < GUARD2);
            while (gm) {
                int src = __ffsll(gm) - 1;
                gm &= gm - 1;
                int rr = __shfl(r, src, 64);
                int cc = __shfl(c, src, 64);
                float invv = __shfl(inv, src, 64);
                int j0 = lane * 4;              // 64 lanes x 4 cols = 256
                float aR[4], aC[4];
#pragma unroll
                for (int q = 0; q < 4; ++q) { aR[q] = b1f[j0 + q]; aC[q] = b1f[j0 + q]; }
                const float* xr = xagg + (size_t)rr * NFEAT;
                const float* xc = xagg + (size_t)cc * NFEAT;
                for (int kk = 0; kk < NFEAT; ++kk) {
                    float vr = xr[kk], vc = xc[kk];   // wave-broadcast loads
                    float4 wv = *((const float4*)(W1f + (size_t)kk * NHID + j0));
                    aR[0] += vr * wv.x; aC[0] += vc * wv.x;
                    aR[1] += vr * wv.y; aC[1] += vc * wv.y;
                    aR[2] += vr * wv.z; aC[2] += vc * wv.z;
                    aR[3] += vr * wv.w; aC[3] += vc * wv.w;
                }
                float dp = 0.f;
#pragma unroll
                for (int q = 0; q < 4; ++q)
                    dp += fmaxf(aR[q], 0.f) * fmaxf(aC[q], 0.f);
                float se = waveSum(dp) * invv;
                if (lane == src) sims = se;
            }
            if (active && l8 == 0) {
                float w2 = (sims >= THRESH) ? sims : 0.f;
                w2csr[pos] = w2;
                if (w2 != 0.f) unsafeAtomicAdd(&deg2[r], w2);
            }
        }
    }
}

// ---- gather2 v5: 8-lane group per node; dinv2 inline; start via bsum ----
__global__ void k_gather2(const float* __restrict__ g, const int* __restrict__ rowptr,
                          const int* __restrict__ bsum,
                          const int* __restrict__ counts, const float* __restrict__ deg2,
                          const float* __restrict__ b2f, const int2* __restrict__ edata,
                          const float* __restrict__ w2csr, float* __restrict__ out, int N) {
    int tid = blockIdx.x * blockDim.x + threadIdx.x;
    int r = tid >> 3;
    int l = tid & 7;
    if (r >= N) return;
    int cnt = counts[r];
    int start = rowptr[r] + bsum[r >> 8] - cnt;
    float dr = 1.0f / sqrtf(1.0f + deg2[r]);
    float drr = dr * dr;
    const float* gr = g + (size_t)r * NCLASS;
    float acc[5];
#pragma unroll
    for (int q = 0; q < 5; ++q) acc[q] = drr * gr[l + 8 * q] + b2f[l + 8 * q];
    for (int k = 0; k < cnt; ++k) {
        int2 ed = edata[start + k];
        float w2 = w2csr[start + k];
        float dc = 1.0f / sqrtf(1.0f + deg2[ed.x]);
        float f = dr * w2 * dc;
        const float* gc = g + (size_t)ed.x * NCLASS;
#pragma unroll
        for (int q = 0; q < 5; ++q) acc[q] += f * gc[l + 8 * q];
    }
    float* po = out + (size_t)r * NCLASS;
#pragma unroll
    for (int q = 0; q < 5; ++q) po[l + 8 * q] = acc[q];
}

extern "C" void kernel_launch(void* const* d_in, const int* in_sizes, int n_in,
                              void* d_out, int out_size, void* d_ws, size_t ws_size,
                              hipStream_t stream) {
    const float* x  = (const float*)d_in[0];
    const int* row  = (const int*)d_in[1];
    const int* col  = (const int*)d_in[2];
    const float* W1 = (const float*)d_in[3];
    const float* b1 = (const float*)d_in[4];
    const float* W2 = (const float*)d_in[5];
    const float* b2 = (const float*)d_in[6];
    float* out = (float*)d_out;
    const int N = in_sizes[0] / NFEAT;
    const int E = in_sizes[1];

    // ---- workspace layout ----
    char* ws = (char*)d_ws;
    size_t off = 0;
    auto alloc = [&](size_t bytes) {
        char* p = ws + off;
        off += (bytes + 255) & ~(size_t)255;
        return p;
    };
    float*   xagg   = (float*)alloc((size_t)N * NFEAT * 4);   // live thru att2e guard
    __half2* hh     = (__half2*)alloc((size_t)N * NHID * 2);  // fp16 h mirror
    __half2* xaggh  = (__half2*)alloc((size_t)N * NFEAT * 2); // fp16 xagg mirror
    float*   w1buf  = (float*)alloc((size_t)E * 4);
    float*   w2csr  = (float*)alloc((size_t)E * 4);
    int2*    edata  = (int2*)alloc((size_t)E * 8);
    int*     esrc   = (int*)alloc((size_t)E * 4);             // CSR source nodes
    float*   nrm    = (float*)alloc((size_t)N * 4);           // layer-1 norms (att1 guard)
    float*   deg    = (float*)alloc((size_t)N * 4);           // degsum layer 1
    int*     counts = (int*)alloc((size_t)N * 4);
    int*     rowptr = (int*)alloc((size_t)N * 4);
    int*     bsum   = (int*)alloc(512 * 4);
    v8h*     w1x    = (v8h*)alloc(4096 * 16);                 // W1 B-fragments (64 KB)
    v8h*     w2x    = (v8h*)alloc(3072 * 16);                 // W2 hi/lo B-fragments (48 KB)
    float*   nrmsq  = (float*)alloc((size_t)N * 4);           // h row sum-of-squares
    float*   deg2   = (float*)alloc((size_t)N * 4);           // layer-2 degree sums
    // int8 screen table overlays xagg (xagg written only later, by k_gather1):
    // [xqi: N*256B interleaved qh|ql][meta: N*16B] = 27.2 MB < 51.2 MB
    signed char* xqi = (signed char*)xagg;
    float4*  meta    = (float4*)(xqi + (size_t)N * 256);
    // dedicated g (so att2e's guard can read xagg while gemm2m writes g):
    size_t gBytes = ((size_t)N * NCLASS * 4 + 255) & ~(size_t)255;
    bool fused = (off + gBytes <= ws_size);
    float* g = fused ? (float*)alloc(gBytes) : xagg;   // fallback: overlay

    const int e16Blocks = (E + 63) / 64;  // 16 edges/wave, 4 waves/block
    const int eBlocks1 = (E + 255) / 256;
    const int nBlocks4 = (N + 3) / 4;
    const int nBlocks8 = (N + 31) / 32;   // 8-lane-group kernels (8 nodes/wave)
    const int scanB    = (N + 255) / 256;
    const int gemmB    = (N + 63) / 64;

    // ---- layer 1 ----
    k_prepw<<<nBlocks4 + 28, 256, 0, stream>>>(x, xqi, meta, nrm, deg, deg2,
                                               counts, nrmsq, W1, w1x, W2, w2x,
                                               N, nBlocks4);
    k_att1<<<e16Blocks, 256, 0, stream>>>(x, xqi, meta, row, col, nrm, w1buf, deg,
                                          counts, E);
    k_scan1<<<scanB, 256, 0, stream>>>(counts, rowptr, bsum, N);
    k_scan2<<<1, 512, 0, stream>>>(bsum, scanB);
    k_fill<<<eBlocks1, 256, 0, stream>>>(row, col, w1buf, deg, rowptr, bsum, edata,
                                         esrc, E);
    k_gather1<<<nBlocks8, 256, 0, stream>>>(x, rowptr, bsum, counts, deg, edata,
                                            xagg, xaggh, N);
    k_gemm1h<<<NSTRIPE, 256, 0, stream>>>(xaggh, w1x, b1, (__half*)hh, nrmsq, N);

    // ---- layer 2 ----
    k_l2fused<<<gemmB + 4096, 256, 0, stream>>>(hh, w2x, g, xagg, W1, b1, esrc,
                                                edata, nrmsq, rowptr + (N - 1),
                                                bsum + ((N - 1) >> 8),
                                                w2csr, deg2, gemmB, N);
    k_gather2<<<nBlocks8, 256, 0, stream>>>(g, rowptr, bsum, counts, deg2, b2, edata,
                                            w2csr, out, N);
}